// Round 1
// baseline (483.283 us; speedup 1.0000x reference)
//
#include <hip/hip_runtime.h>
#include <math.h>

#define BB 32
#define HH 512
#define WW 512
#define CC 3
#define LL 4

static __device__ __forceinline__ float softplusf_(float x) {
    if (x > 20.f) return x;
    return log1pf(expf(x));
}

static __device__ __forceinline__ int imin_(int a, int b) { return a < b ? a : b; }
static __device__ __forceinline__ int imax_(int a, int b) { return a > b ? a : b; }

// ---------------- prep: normalized per-level kernels + KL ----------------
__global__ void prep_kernel(const float* __restrict__ loc, const float* __restrict__ scale,
                            const float* __restrict__ eps, float* __restrict__ knorm,
                            double* __restrict__ kl_out) {
    if (threadIdx.x != 0 || blockIdx.x != 0) return;
    double kl = 0.0;
    for (int i = 0; i < 27; ++i) {
        float s = softplusf_(scale[i]);
        float m = loc[i];
        kl += -log((double)s) + 0.5 * ((double)s * s + (double)m * m) - 0.5;
    }
    *kl_out = kl;
    for (int l = 0; l < LL; ++l) {
        for (int c = 0; c < CC; ++c) {
            float v[9];
            float sum = 0.f;
            for (int t = 0; t < 9; ++t) {
                int idx = t * 3 + c;            // [KH*KW, C] flattened
                float s = softplusf_(scale[idx]);
                float val = loc[idx] + s * eps[l * 27 + idx];
                if (t == 4) val = 0.f;          // center mask
                v[t] = val;
                sum += val;
            }
            float denom = sum + 1e-7f;
            for (int t = 0; t < 9; ++t)
                knorm[l * 27 + t * 3 + c] = v[t] / denom;
        }
    }
}

// ---------------- antialiased bilinear downsample (exact jax.image.resize) ----------------
template <int F>
__global__ void downsample_kernel(const float* __restrict__ x, float* __restrict__ ds) {
    constexpr int TH = HH / F, TW = WW / F, TAPS = 2 * F;
    int idx = blockIdx.x * blockDim.x + threadIdx.x;
    if (idx >= BB * TH * TW) return;
    int ow = idx % TW;
    int tt = idx / TW;
    int oh = tt % TH;
    int b = tt / TH;

    float whv[TAPS], wwv[TAPS];
    float sfh = (oh + 0.5f) * F - 0.5f;
    float sfw = (ow + 0.5f) * F - 0.5f;
    int jh0 = oh * F - F / 2;
    int jw0 = ow * F - F / 2;
    float hsum = 0.f, wsum = 0.f;
    for (int t = 0; t < TAPS; ++t) {
        int jh = jh0 + t;
        float wg = (jh >= 0 && jh < HH) ? (1.f - fabsf(jh - sfh) * (1.0f / F)) : 0.f;
        whv[t] = wg; hsum += wg;
        int jw = jw0 + t;
        float wg2 = (jw >= 0 && jw < WW) ? (1.f - fabsf(jw - sfw) * (1.0f / F)) : 0.f;
        wwv[t] = wg2; wsum += wg2;
    }
    float inv = 1.f / (hsum * wsum);

    float acc0 = 0.f, acc1 = 0.f, acc2 = 0.f;
    for (int th = 0; th < TAPS; ++th) {
        int jh = jh0 + th;
        if (jh < 0 || jh >= HH) continue;
        float wh = whv[th];
        const float* row = x + ((size_t)b * HH + jh) * WW * CC;
        for (int tw = 0; tw < TAPS; ++tw) {
            int jw = jw0 + tw;
            if (jw < 0 || jw >= WW) continue;
            float wgt = wh * wwv[tw];
            const float* p = row + (size_t)jw * CC;
            acc0 += wgt * p[0];
            acc1 += wgt * p[1];
            acc2 += wgt * p[2];
        }
    }
    float* o = ds + (size_t)idx * CC;
    o[0] = acc0 * inv;
    o[1] = acc1 * inv;
    o[2] = acc2 * inv;
}

// ---------------- per-level channel-summed residual: es = sum_c (ds - dwconv(ds)) ----------------
template <int F>
__global__ void errsum_kernel(const float* __restrict__ ds, const float* __restrict__ knorm_all,
                              int lvl, float* __restrict__ es) {
    constexpr int TH = HH / F, TW = WW / F;
    int idx = blockIdx.x * blockDim.x + threadIdx.x;
    if (idx >= BB * TH * TW) return;
    int ow = idx % TW;
    int tt = idx / TW;
    int oh = tt % TH;
    int b = tt / TH;
    const float* kn = knorm_all + lvl * 27;
    const float* img = ds + (size_t)b * TH * TW * CC;
    float e = 0.f;
    for (int c = 0; c < CC; ++c) {
        float conv = 0.f;
        #pragma unroll
        for (int dh = -1; dh <= 1; ++dh) {
            int hh = oh + dh;
            if (hh < 0 || hh >= TH) continue;
            #pragma unroll
            for (int dw = -1; dw <= 1; ++dw) {
                int wwi = ow + dw;
                if (wwi < 0 || wwi >= TW) continue;
                conv += kn[((dh + 1) * 3 + (dw + 1)) * 3 + c] * img[((size_t)hh * TW + wwi) * CC + c];
            }
        }
        e += img[((size_t)oh * TW + ow) * CC + c] - conv;
    }
    es[idx] = e;
}

// ---------------- bilinear upsample tap (antialias=false, edge-clamped) ----------------
template <int F>
static __device__ __forceinline__ float bilin_(const float* __restrict__ es, int b, int h, int w) {
    constexpr int TH = HH / F, TW = WW / F;
    float sfh = (h + 0.5f) * (1.0f / F) - 0.5f;
    float sfw = (w + 0.5f) * (1.0f / F) - 0.5f;
    int h0 = (int)floorf(sfh);
    float fh = sfh - (float)h0;
    int w0 = (int)floorf(sfw);
    float fw = sfw - (float)w0;
    int h0c = imax_(h0, 0);
    int h1c = imin_(h0 + 1, TH - 1);
    int w0c = imax_(w0, 0);
    int w1c = imin_(w0 + 1, TW - 1);
    const float* base = es + (size_t)b * TH * TW;
    float v00 = base[(size_t)h0c * TW + w0c];
    float v01 = base[(size_t)h0c * TW + w1c];
    float v10 = base[(size_t)h1c * TW + w0c];
    float v11 = base[(size_t)h1c * TW + w1c];
    float top = v00 + fw * (v01 - v00);
    float bot = v10 + fw * (v11 - v10);
    return top + fh * (bot - top);
}

// ---------------- fused: level-1 residual + 3 upsampled levels, square, reduce ----------------
__global__ void fused_kernel(const float* __restrict__ x, const float* __restrict__ knorm,
                             const float* __restrict__ es2, const float* __restrict__ es3,
                             const float* __restrict__ es4, double* __restrict__ partials) {
    const int total = BB * HH * WW;
    double acc = 0.0;
    for (int idx = blockIdx.x * blockDim.x + threadIdx.x; idx < total;
         idx += gridDim.x * blockDim.x) {
        int w = idx % WW;
        int tt = idx / WW;
        int h = tt % HH;
        int b = tt / HH;
        const float* img = x + (size_t)b * HH * WW * CC;
        float e = 0.f;
        for (int c = 0; c < CC; ++c) {
            float conv = 0.f;
            #pragma unroll
            for (int dh = -1; dh <= 1; ++dh) {
                int hh = h + dh;
                if (hh < 0 || hh >= HH) continue;
                #pragma unroll
                for (int dw = -1; dw <= 1; ++dw) {
                    int wi = w + dw;
                    if (wi < 0 || wi >= WW) continue;
                    conv += knorm[((dh + 1) * 3 + (dw + 1)) * 3 + c] *
                            img[((size_t)hh * WW + wi) * CC + c];
                }
            }
            e += img[((size_t)h * WW + w) * CC + c] - conv;
        }
        e += bilin_<2>(es2, b, h, w);
        e += bilin_<4>(es3, b, h, w);
        e += bilin_<8>(es4, b, h, w);
        acc += (double)e * (double)e;
    }
    __shared__ double sm[256];
    sm[threadIdx.x] = acc;
    __syncthreads();
    for (int s = 128; s > 0; s >>= 1) {
        if (threadIdx.x < (unsigned)s) sm[threadIdx.x] += sm[threadIdx.x + s];
        __syncthreads();
    }
    if (threadIdx.x == 0) partials[blockIdx.x] = sm[0];
}

__global__ void final_kernel(const double* __restrict__ partials, int n,
                             const double* __restrict__ kl, float* __restrict__ out) {
    __shared__ double sm[256];
    double acc = 0.0;
    for (int i = threadIdx.x; i < n; i += blockDim.x) acc += partials[i];
    sm[threadIdx.x] = acc;
    __syncthreads();
    for (int s = 128; s > 0; s >>= 1) {
        if (threadIdx.x < (unsigned)s) sm[threadIdx.x] += sm[threadIdx.x + s];
        __syncthreads();
    }
    if (threadIdx.x == 0) out[0] = (float)(sm[0] / (double)BB + (double)LL * kl[0]);
}

extern "C" void kernel_launch(void* const* d_in, const int* in_sizes, int n_in,
                              void* d_out, int out_size, void* d_ws, size_t ws_size,
                              hipStream_t stream) {
    const float* x = (const float*)d_in[0];          // [32,512,512,3]
    const float* loc = (const float*)d_in[1];        // [3,3,3,1]
    const float* scale = (const float*)d_in[2];      // [3,3,3,1]
    const float* eps = (const float*)d_in[3];        // [4,3,3,3,1]
    float* out = (float*)d_out;

    char* ws = (char*)d_ws;
    float* knorm = (float*)(ws + 0);                 // 4*27 floats
    double* kl = (double*)(ws + 512);                // 1 double
    const int NPART = 4096;
    double* partials = (double*)(ws + 1024);         // 4096 doubles -> ends 33792

    size_t off = 65536;
    float* ds2 = (float*)(ws + off); off += (size_t)BB * 256 * 256 * 3 * 4;  // 25165824
    float* es2 = (float*)(ws + off); off += (size_t)BB * 256 * 256 * 4;      // 8388608
    float* ds3 = (float*)(ws + off); off += (size_t)BB * 128 * 128 * 3 * 4;  // 6291456
    float* es3 = (float*)(ws + off); off += (size_t)BB * 128 * 128 * 4;      // 2097152
    float* ds4 = (float*)(ws + off); off += (size_t)BB * 64 * 64 * 3 * 4;    // 1572864
    float* es4 = (float*)(ws + off); off += (size_t)BB * 64 * 64 * 4;        // 524288
    (void)ws_size; (void)in_sizes; (void)n_in; (void)out_size;

    prep_kernel<<<1, 64, 0, stream>>>(loc, scale, eps, knorm, kl);

    {
        int total = BB * 256 * 256;
        downsample_kernel<2><<<(total + 255) / 256, 256, 0, stream>>>(x, ds2);
        errsum_kernel<2><<<(total + 255) / 256, 256, 0, stream>>>(ds2, knorm, 1, es2);
    }
    {
        int total = BB * 128 * 128;
        downsample_kernel<4><<<(total + 255) / 256, 256, 0, stream>>>(x, ds3);
        errsum_kernel<4><<<(total + 255) / 256, 256, 0, stream>>>(ds3, knorm, 2, es3);
    }
    {
        int total = BB * 64 * 64;
        downsample_kernel<8><<<(total + 255) / 256, 256, 0, stream>>>(x, ds4);
        errsum_kernel<8><<<(total + 255) / 256, 256, 0, stream>>>(ds4, knorm, 3, es4);
    }

    fused_kernel<<<NPART, 256, 0, stream>>>(x, knorm, es2, es3, es4, partials);
    final_kernel<<<1, 256, 0, stream>>>(partials, NPART, kl, out);
}

// Round 2
// 268.550 us; speedup vs baseline: 1.7996x; 1.7996x over previous
//
#include <hip/hip_runtime.h>
#include <hip/hip_fp16.h>
#include <math.h>

#define BB 32
#define HH 512
#define WW 512
#define CC 3
#define LL 4

static __device__ __forceinline__ float softplusf_(float x) {
    if (x > 20.f) return x;
    return log1pf(expf(x));
}

// ---------------- prep: normalized per-level kernels + KL ----------------
__global__ void prep_kernel(const float* __restrict__ loc, const float* __restrict__ scale,
                            const float* __restrict__ eps, float* __restrict__ knorm,
                            double* __restrict__ kl_out) {
    if (threadIdx.x != 0 || blockIdx.x != 0) return;
    double kl = 0.0;
    for (int i = 0; i < 27; ++i) {
        float s = softplusf_(scale[i]);
        float m = loc[i];
        kl += -log((double)s) + 0.5 * ((double)s * s + (double)m * m) - 0.5;
    }
    *kl_out = kl;
    for (int l = 0; l < LL; ++l) {
        for (int c = 0; c < CC; ++c) {
            float v[9];
            float sum = 0.f;
            for (int t = 0; t < 9; ++t) {
                int idx = t * 3 + c;
                float s = softplusf_(scale[idx]);
                float val = loc[idx] + s * eps[l * 27 + idx];
                if (t == 4) val = 0.f;
                v[t] = val;
                sum += val;
            }
            float denom = sum + 1e-7f;
            for (int t = 0; t < 9; ++t)
                knorm[l * 27 + t * 3 + c] = v[t] / denom;
        }
    }
}

// ---------------- horizontal antialiased downsample passes (separable) ----------------
// grid = BB*HH blocks, 256 threads; one image row per block, staged in LDS.

__global__ void hpass2_kernel(const float* __restrict__ x, __half* __restrict__ xh2) {
    __shared__ float row[WW * CC];
    int bh = blockIdx.x;
    const float4* src = (const float4*)(x + (size_t)bh * WW * CC);
    float4* dstv = (float4*)row;
    for (int i = threadIdx.x; i < WW * CC / 4; i += 256) dstv[i] = src[i];
    __syncthreads();
    int ow = threadIdx.x;                 // 0..255
    float sfw = 2.f * ow + 0.5f;          // (ow+0.5)*2 - 0.5
    int j0 = 2 * ow - 1;
    float wv[4]; float s = 0.f;
    #pragma unroll
    for (int k = 0; k < 4; ++k) {
        int j = j0 + k;
        float w = (j >= 0 && j < WW) ? (1.f - fabsf(j - sfw) * 0.5f) : 0.f;
        wv[k] = w; s += w;
    }
    float inv = 1.f / s;
    float a0 = 0, a1 = 0, a2 = 0;
    #pragma unroll
    for (int k = 0; k < 4; ++k) {
        int j = j0 + k; j = j < 0 ? 0 : (j >= WW ? WW - 1 : j);
        float w = wv[k] * inv;
        a0 += w * row[j * 3 + 0];
        a1 += w * row[j * 3 + 1];
        a2 += w * row[j * 3 + 2];
    }
    __half* o = xh2 + ((size_t)bh * 256 + ow) * 3;
    o[0] = __float2half_rn(a0); o[1] = __float2half_rn(a1); o[2] = __float2half_rn(a2);
}

__global__ void hpass48_kernel(const float* __restrict__ x, __half* __restrict__ xh4,
                               __half* __restrict__ xh8) {
    __shared__ float row[WW * CC];
    int bh = blockIdx.x;
    const float4* src = (const float4*)(x + (size_t)bh * WW * CC);
    float4* dstv = (float4*)row;
    for (int i = threadIdx.x; i < WW * CC / 4; i += 256) dstv[i] = src[i];
    __syncthreads();
    int t = threadIdx.x;
    if (t < 128) {                        // F=4, 8 taps
        int ow = t;
        float sfw = 4.f * ow + 1.5f;
        int j0 = 4 * ow - 2;
        float wv[8]; float s = 0.f;
        #pragma unroll
        for (int k = 0; k < 8; ++k) {
            int j = j0 + k;
            float w = (j >= 0 && j < WW) ? (1.f - fabsf(j - sfw) * 0.25f) : 0.f;
            wv[k] = w; s += w;
        }
        float inv = 1.f / s;
        float a0 = 0, a1 = 0, a2 = 0;
        #pragma unroll
        for (int k = 0; k < 8; ++k) {
            int j = j0 + k; j = j < 0 ? 0 : (j >= WW ? WW - 1 : j);
            float w = wv[k] * inv;
            a0 += w * row[j * 3 + 0];
            a1 += w * row[j * 3 + 1];
            a2 += w * row[j * 3 + 2];
        }
        __half* o = xh4 + ((size_t)bh * 128 + ow) * 3;
        o[0] = __float2half_rn(a0); o[1] = __float2half_rn(a1); o[2] = __float2half_rn(a2);
    } else if (t < 192) {                 // F=8, 16 taps
        int ow = t - 128;
        float sfw = 8.f * ow + 3.5f;
        int j0 = 8 * ow - 4;
        float wv[16]; float s = 0.f;
        #pragma unroll
        for (int k = 0; k < 16; ++k) {
            int j = j0 + k;
            float w = (j >= 0 && j < WW) ? (1.f - fabsf(j - sfw) * 0.125f) : 0.f;
            wv[k] = w; s += w;
        }
        float inv = 1.f / s;
        float a0 = 0, a1 = 0, a2 = 0;
        #pragma unroll
        for (int k = 0; k < 16; ++k) {
            int j = j0 + k; j = j < 0 ? 0 : (j >= WW ? WW - 1 : j);
            float w = wv[k] * inv;
            a0 += w * row[j * 3 + 0];
            a1 += w * row[j * 3 + 1];
            a2 += w * row[j * 3 + 2];
        }
        __half* o = xh8 + ((size_t)bh * 64 + ow) * 3;
        o[0] = __float2half_rn(a0); o[1] = __float2half_rn(a1); o[2] = __float2half_rn(a2);
    }
}

// ---------------- level kernel: vertical pass (into LDS, with halo) + conv + channel-sum ----------------
template <int F>
__global__ void level_kernel(const __half* __restrict__ xh, const float* __restrict__ knorm_all,
                             int lvl, float* __restrict__ es) {
    constexpr int TH = HH / F, TW = WW / F, TAPS = 2 * F;
    __shared__ float dst[34][34 * 3];     // ds tile with halo, zero-padded
    __shared__ float wv[34][TAPS];
    __shared__ int jh0s[34];
    __shared__ float kn[27];
    int owb = blockIdx.x * 32;
    int ohb = blockIdx.y * 32;
    int b = blockIdx.z;
    int tid = threadIdx.x;
    if (tid < 27) kn[tid] = knorm_all[lvl * 27 + tid];
    if (tid < 34) {
        int oh = ohb - 1 + tid;
        int j0 = oh * F - F / 2;
        jh0s[tid] = j0;
        if (oh < 0 || oh >= TH) {
            for (int k = 0; k < TAPS; ++k) wv[tid][k] = 0.f;
        } else {
            float sfh = (oh + 0.5f) * F - 0.5f;
            float tmp[TAPS]; float s = 0.f;
            #pragma unroll
            for (int k = 0; k < TAPS; ++k) {
                int j = j0 + k;
                float w = (j >= 0 && j < HH) ? (1.f - fabsf(j - sfh) * (1.0f / F)) : 0.f;
                tmp[k] = w; s += w;
            }
            float inv = 1.f / s;
            #pragma unroll
            for (int k = 0; k < TAPS; ++k) wv[tid][k] = tmp[k] * inv;
        }
    }
    __syncthreads();
    const __half* xb = xh + (size_t)b * HH * TW * CC;
    for (int i = tid; i < 34 * 34 * 3; i += 256) {
        int r = i / (34 * 3);
        int jc = i % (34 * 3);
        int col = jc / 3;
        int c = jc % 3;
        int ow = owb - 1 + col;
        float v = 0.f;
        if (ow >= 0 && ow < TW) {
            int j0 = jh0s[r];
            #pragma unroll
            for (int k = 0; k < TAPS; ++k) {
                int jh = j0 + k;
                jh = jh < 0 ? 0 : (jh >= HH ? HH - 1 : jh);
                v += wv[r][k] * __half2float(xb[((size_t)jh * TW + ow) * 3 + c]);
            }
        }
        dst[r][jc] = v;
    }
    __syncthreads();
    for (int i = tid; i < 32 * 32; i += 256) {
        int wl = i % 32, hl = i / 32;
        float e = 0.f;
        #pragma unroll
        for (int c = 0; c < 3; ++c) {
            float conv = 0.f;
            #pragma unroll
            for (int dh = 0; dh < 3; ++dh)
                #pragma unroll
                for (int dw = 0; dw < 3; ++dw)
                    conv += kn[(dh * 3 + dw) * 3 + c] * dst[hl + dh][(wl + dw) * 3 + c];
            e += dst[hl + 1][(wl + 1) * 3 + c] - conv;
        }
        es[((size_t)b * TH + (ohb + hl)) * TW + (owb + wl)] = e;
    }
}

// ---------------- fused: level-1 residual + 3 upsampled levels, square, reduce ----------------
#define FTW 32
#define FTH 8
__global__ void fused_kernel(const float* __restrict__ x, const float* __restrict__ knorm,
                             const float* __restrict__ es2, const float* __restrict__ es3,
                             const float* __restrict__ es4, double* __restrict__ partials) {
    __shared__ float xt[10][34 * 3];
    __shared__ float e2t[6][18];
    __shared__ float e3t[4][10];
    __shared__ float e4t[3][6];
    __shared__ float kn[27];
    __shared__ double sm[256];
    int b = blockIdx.z;
    int hb = blockIdx.y * FTH;
    int wb = blockIdx.x * FTW;
    int tid = threadIdx.x;
    if (tid < 27) kn[tid] = knorm[tid];
    const float* xb = x + (size_t)b * HH * WW * CC;
    for (int i = tid; i < 10 * 34 * 3; i += 256) {
        int r = i / (34 * 3), jc = i % (34 * 3);
        int gh = hb - 1 + r;
        int gw = wb - 1 + jc / 3;
        int c = jc % 3;
        xt[r][jc] = (gh >= 0 && gh < HH && gw >= 0 && gw < WW)
                        ? xb[((size_t)gh * WW + gw) * 3 + c] : 0.f;
    }
    {
        const float* e2b = es2 + (size_t)b * 256 * 256;
        int h0 = hb / 2 - 1, w0 = wb / 2 - 1;
        for (int i = tid; i < 6 * 18; i += 256) {
            int r = i / 18, cl = i % 18;
            int gh = h0 + r; gh = gh < 0 ? 0 : (gh > 255 ? 255 : gh);
            int gw = w0 + cl; gw = gw < 0 ? 0 : (gw > 255 ? 255 : gw);
            e2t[r][cl] = e2b[(size_t)gh * 256 + gw];
        }
        const float* e3b = es3 + (size_t)b * 128 * 128;
        int h03 = hb / 4 - 1, w03 = wb / 4 - 1;
        for (int i = tid; i < 4 * 10; i += 256) {
            int r = i / 10, cl = i % 10;
            int gh = h03 + r; gh = gh < 0 ? 0 : (gh > 127 ? 127 : gh);
            int gw = w03 + cl; gw = gw < 0 ? 0 : (gw > 127 ? 127 : gw);
            e3t[r][cl] = e3b[(size_t)gh * 128 + gw];
        }
        const float* e4b = es4 + (size_t)b * 64 * 64;
        int h04 = hb / 8 - 1, w04 = wb / 8 - 1;
        for (int i = tid; i < 3 * 6; i += 256) {
            int r = i / 6, cl = i % 6;
            int gh = h04 + r; gh = gh < 0 ? 0 : (gh > 63 ? 63 : gh);
            int gw = w04 + cl; gw = gw < 0 ? 0 : (gw > 63 ? 63 : gw);
            e4t[r][cl] = e4b[(size_t)gh * 64 + gw];
        }
    }
    __syncthreads();
    int wl = tid % FTW, hl = tid / FTW;
    int h = hb + hl, w = wb + wl;
    float e = 0.f;
    #pragma unroll
    for (int c = 0; c < 3; ++c) {
        float conv = 0.f;
        #pragma unroll
        for (int dh = 0; dh < 3; ++dh)
            #pragma unroll
            for (int dw = 0; dw < 3; ++dw)
                conv += kn[(dh * 3 + dw) * 3 + c] * xt[hl + dh][(wl + dw) * 3 + c];
        e += xt[hl + 1][(wl + 1) * 3 + c] - conv;
    }
    {   // es2 bilinear (F=2)
        float sfh = 0.5f * h - 0.25f, sfw = 0.5f * w - 0.25f;
        int h0 = (int)floorf(sfh), w0 = (int)floorf(sfw);
        float fh = sfh - h0, fw = sfw - w0;
        int rh = h0 - (hb / 2 - 1), rw = w0 - (wb / 2 - 1);
        float v00 = e2t[rh][rw], v01 = e2t[rh][rw + 1];
        float v10 = e2t[rh + 1][rw], v11 = e2t[rh + 1][rw + 1];
        float top = v00 + fw * (v01 - v00);
        float bot = v10 + fw * (v11 - v10);
        e += top + fh * (bot - top);
    }
    {   // es3 bilinear (F=4)
        float sfh = 0.25f * h - 0.375f, sfw = 0.25f * w - 0.375f;
        int h0 = (int)floorf(sfh), w0 = (int)floorf(sfw);
        float fh = sfh - h0, fw = sfw - w0;
        int rh = h0 - (hb / 4 - 1), rw = w0 - (wb / 4 - 1);
        float v00 = e3t[rh][rw], v01 = e3t[rh][rw + 1];
        float v10 = e3t[rh + 1][rw], v11 = e3t[rh + 1][rw + 1];
        float top = v00 + fw * (v01 - v00);
        float bot = v10 + fw * (v11 - v10);
        e += top + fh * (bot - top);
    }
    {   // es4 bilinear (F=8)
        float sfh = 0.125f * h - 0.4375f, sfw = 0.125f * w - 0.4375f;
        int h0 = (int)floorf(sfh), w0 = (int)floorf(sfw);
        float fh = sfh - h0, fw = sfw - w0;
        int rh = h0 - (hb / 8 - 1), rw = w0 - (wb / 8 - 1);
        float v00 = e4t[rh][rw], v01 = e4t[rh][rw + 1];
        float v10 = e4t[rh + 1][rw], v11 = e4t[rh + 1][rw + 1];
        float top = v00 + fw * (v01 - v00);
        float bot = v10 + fw * (v11 - v10);
        e += top + fh * (bot - top);
    }
    sm[tid] = (double)e * (double)e;
    __syncthreads();
    for (int s = 128; s > 0; s >>= 1) {
        if (tid < s) sm[tid] += sm[tid + s];
        __syncthreads();
    }
    if (tid == 0) {
        int blk = ((b * gridDim.y) + blockIdx.y) * gridDim.x + blockIdx.x;
        partials[blk] = sm[0];
    }
}

__global__ void final_kernel(const double* __restrict__ partials, int n,
                             const double* __restrict__ kl, float* __restrict__ out) {
    __shared__ double sm[256];
    double acc = 0.0;
    for (int i = threadIdx.x; i < n; i += blockDim.x) acc += partials[i];
    sm[threadIdx.x] = acc;
    __syncthreads();
    for (int s = 128; s > 0; s >>= 1) {
        if (threadIdx.x < (unsigned)s) sm[threadIdx.x] += sm[threadIdx.x + s];
        __syncthreads();
    }
    if (threadIdx.x == 0) out[0] = (float)(sm[0] / (double)BB + (double)LL * kl[0]);
}

extern "C" void kernel_launch(void* const* d_in, const int* in_sizes, int n_in,
                              void* d_out, int out_size, void* d_ws, size_t ws_size,
                              hipStream_t stream) {
    const float* x = (const float*)d_in[0];
    const float* loc = (const float*)d_in[1];
    const float* scale = (const float*)d_in[2];
    const float* eps = (const float*)d_in[3];
    float* out = (float*)d_out;

    char* ws = (char*)d_ws;
    float* knorm = (float*)(ws + 0);                  // 432 B
    double* kl = (double*)(ws + 512);                 // 8 B
    double* partials = (double*)(ws + 1024);          // 32768*8 = 262144 -> ends 263168
    float* es4 = (float*)(ws + 270336);               // 524288  -> ends 794624
    float* es3 = (float*)(ws + 794624);               // 2097152 -> ends 2891776
    float* es2 = (float*)(ws + 2891776);              // 8388608 -> ends 11280384
    // xh region (reused): xh4+xh8 first, then xh2 overwrites
    __half* xh4 = (__half*)(ws + 11534336);           // 12582912
    __half* xh8 = (__half*)(ws + 11534336 + 12582912);// 6291456 -> ends 30408704
    __half* xh2 = (__half*)(ws + 11534336);           // 25165824 -> ends 36700160
    (void)ws_size; (void)in_sizes; (void)n_in; (void)out_size;

    prep_kernel<<<1, 64, 0, stream>>>(loc, scale, eps, knorm, kl);

    hpass48_kernel<<<BB * HH, 256, 0, stream>>>(x, xh4, xh8);
    level_kernel<8><<<dim3(2, 2, BB), 256, 0, stream>>>(xh8, knorm, 3, es4);
    level_kernel<4><<<dim3(4, 4, BB), 256, 0, stream>>>(xh4, knorm, 2, es3);

    hpass2_kernel<<<BB * HH, 256, 0, stream>>>(x, xh2);
    level_kernel<2><<<dim3(8, 8, BB), 256, 0, stream>>>(xh2, knorm, 1, es2);

    fused_kernel<<<dim3(WW / FTW, HH / FTH, BB), 256, 0, stream>>>(x, knorm, es2, es3, es4, partials);
    final_kernel<<<1, 256, 0, stream>>>(partials, WW / FTW * (HH / FTH) * BB, kl, out);
}

// Round 3
// 184.496 us; speedup vs baseline: 2.6195x; 1.4556x over previous
//
#include <hip/hip_runtime.h>
#include <hip/hip_fp16.h>
#include <math.h>

#define BB 32
#define HH 512
#define WW 512
#define CC 3
#define LL 4

static __device__ __forceinline__ float softplusf_(float x) {
    if (x > 20.f) return x;
    return log1pf(expf(x));
}
static __device__ __forceinline__ int iclamp_(int v, int lo, int hi) {
    return v < lo ? lo : (v > hi ? hi : v);
}

// ---------------- prep: normalized per-level kernels + KL ----------------
__global__ void prep_kernel(const float* __restrict__ loc, const float* __restrict__ scale,
                            const float* __restrict__ eps, float* __restrict__ knorm,
                            double* __restrict__ kl_out) {
    int tid = threadIdx.x;   // 64 threads
    float klv = 0.f;
    if (tid < 27) {
        float s = softplusf_(scale[tid]);
        float m = loc[tid];
        klv = -logf(s) + 0.5f * (s * s + m * m) - 0.5f;
    }
    #pragma unroll
    for (int off = 32; off; off >>= 1) klv += __shfl_down(klv, off);
    if (tid == 0) *kl_out = (double)klv;
    if (tid < 12) {
        int l = tid / 3;
        int c = tid - l * 3;
        float v[9];
        float sum = 0.f;
        #pragma unroll
        for (int t = 0; t < 9; ++t) {
            int idx = t * 3 + c;
            float s = softplusf_(scale[idx]);
            float val = loc[idx] + s * eps[l * 27 + idx];
            if (t == 4) val = 0.f;
            v[t] = val;
            sum += val;
        }
        float denom = sum + 1e-7f;
        #pragma unroll
        for (int t = 0; t < 9; ++t)
            knorm[l * 27 + t * 3 + c] = v[t] / denom;
    }
}

// ---------------- single-read horizontal downsample: xh2, xh4, xh8 ----------------
// one image row per block; any output pointer may be null (skipped).
__global__ void hpass_kernel(const float* __restrict__ x, __half* __restrict__ xh2,
                             __half* __restrict__ xh4, __half* __restrict__ xh8) {
    __shared__ __align__(16) float row[WW * CC];
    int bh = blockIdx.x;                       // b*512 + h, < 16384
    int tid = threadIdx.x;
    const float4* src = (const float4*)(x + bh * (WW * CC));
    float4* dstv = (float4*)row;
    for (int i = tid; i < WW * CC / 4; i += 256) dstv[i] = src[i];
    __syncthreads();

    if (xh2) {                                  // F=2: all 256 threads
        int ow = tid;
        float sfw = 2.f * ow + 0.5f;
        int j0 = 2 * ow - 1;
        float wv[4]; float s = 0.f;
        #pragma unroll
        for (int k = 0; k < 4; ++k) {
            int j = j0 + k;
            float w = (j >= 0 && j < WW) ? (1.f - fabsf(j - sfw) * 0.5f) : 0.f;
            wv[k] = w; s += w;
        }
        float inv = 1.f / s;
        float a0 = 0, a1 = 0, a2 = 0;
        #pragma unroll
        for (int k = 0; k < 4; ++k) {
            int j = iclamp_(j0 + k, 0, WW - 1);
            float w = wv[k] * inv;
            a0 += w * row[j * 3 + 0];
            a1 += w * row[j * 3 + 1];
            a2 += w * row[j * 3 + 2];
        }
        __half* o = xh2 + bh * 768 + ow * 3;
        o[0] = __float2half_rn(a0); o[1] = __float2half_rn(a1); o[2] = __float2half_rn(a2);
    }
    if (xh4 && tid >= 64 && tid < 192) {        // F=4: 128 threads
        int ow = tid - 64;
        float sfw = 4.f * ow + 1.5f;
        int j0 = 4 * ow - 2;
        float wv[8]; float s = 0.f;
        #pragma unroll
        for (int k = 0; k < 8; ++k) {
            int j = j0 + k;
            float w = (j >= 0 && j < WW) ? (1.f - fabsf(j - sfw) * 0.25f) : 0.f;
            wv[k] = w; s += w;
        }
        float inv = 1.f / s;
        float a0 = 0, a1 = 0, a2 = 0;
        #pragma unroll
        for (int k = 0; k < 8; ++k) {
            int j = iclamp_(j0 + k, 0, WW - 1);
            float w = wv[k] * inv;
            a0 += w * row[j * 3 + 0];
            a1 += w * row[j * 3 + 1];
            a2 += w * row[j * 3 + 2];
        }
        __half* o = xh4 + bh * 384 + ow * 3;
        o[0] = __float2half_rn(a0); o[1] = __float2half_rn(a1); o[2] = __float2half_rn(a2);
    }
    if (xh8 && tid >= 192) {                    // F=8: 64 threads
        int ow = tid - 192;
        float sfw = 8.f * ow + 3.5f;
        int j0 = 8 * ow - 4;
        float wv[16]; float s = 0.f;
        #pragma unroll
        for (int k = 0; k < 16; ++k) {
            int j = j0 + k;
            float w = (j >= 0 && j < WW) ? (1.f - fabsf(j - sfw) * 0.125f) : 0.f;
            wv[k] = w; s += w;
        }
        float inv = 1.f / s;
        float a0 = 0, a1 = 0, a2 = 0;
        #pragma unroll
        for (int k = 0; k < 16; ++k) {
            int j = iclamp_(j0 + k, 0, WW - 1);
            float w = wv[k] * inv;
            a0 += w * row[j * 3 + 0];
            a1 += w * row[j * 3 + 1];
            a2 += w * row[j * 3 + 2];
        }
        __half* o = xh8 + bh * 192 + ow * 3;
        o[0] = __float2half_rn(a0); o[1] = __float2half_rn(a1); o[2] = __float2half_rn(a2);
    }
}

// ---------------- per-level: vertical pass + conv + channel-sum ----------------
template <int F>
static __device__ __forceinline__ void level_body(const __half* __restrict__ xh,
                                                  const float* __restrict__ knorm_all, int lvl,
                                                  float* __restrict__ es, int bx, int by, int b,
                                                  float* smem) {
    constexpr int TH = HH / F, TW = WW / F, TAPS = 2 * F;
    constexpr int TW3 = TW * 3;
    float* dst = smem;                           // [34][104]
    float* wv = smem + 34 * 104;                 // [34][TAPS]
    int* jh0s = (int*)(smem + 34 * 104 + 34 * TAPS);
    float* kn = smem + 34 * 104 + 34 * TAPS + 34;
    int owb = bx * 32, ohb = by * 32;
    int tid = threadIdx.x;
    if (tid < 27) kn[tid] = knorm_all[lvl * 27 + tid];
    if (tid < 34) {
        int oh = ohb - 1 + tid;
        int j0 = oh * F - F / 2;
        jh0s[tid] = j0;
        if (oh < 0 || oh >= TH) {
            for (int k = 0; k < TAPS; ++k) wv[tid * TAPS + k] = 0.f;
        } else {
            float sfh = (oh + 0.5f) * F - 0.5f;
            float tmp[TAPS]; float s = 0.f;
            #pragma unroll
            for (int k = 0; k < TAPS; ++k) {
                int j = j0 + k;
                float w = (j >= 0 && j < HH) ? (1.f - fabsf(j - sfh) * (1.0f / F)) : 0.f;
                tmp[k] = w; s += w;
            }
            float inv = 1.f / s;
            #pragma unroll
            for (int k = 0; k < TAPS; ++k) wv[tid * TAPS + k] = tmp[k] * inv;
        }
    }
    __syncthreads();
    const __half* xb = xh + b * (HH * TW3);
    int dwb = (owb - 1) * 3;
    for (int i = tid; i < 34 * 32; i += 256) {
        int r = i >> 5, c4 = (i & 31) * 4;
        if (c4 >= 102) continue;
        int dw0 = dwb + c4;
        bool v0ok = (unsigned)(dw0 + 0) < (unsigned)TW3;
        bool v1ok = (unsigned)(dw0 + 1) < (unsigned)TW3;
        bool v2ok = (unsigned)(dw0 + 2) < (unsigned)TW3;
        bool v3ok = (unsigned)(dw0 + 3) < (unsigned)TW3;
        int j0 = jh0s[r];
        float v0 = 0, v1 = 0, v2 = 0, v3 = 0;
        #pragma unroll
        for (int k = 0; k < TAPS; ++k) {
            int jh = iclamp_(j0 + k, 0, HH - 1);
            float wk = wv[r * TAPS + k];
            const __half* p = xb + jh * TW3;
            if (v0ok) v0 += wk * __half2float(p[dw0 + 0]);
            if (v1ok) v1 += wk * __half2float(p[dw0 + 1]);
            if (v2ok) v2 += wk * __half2float(p[dw0 + 2]);
            if (v3ok) v3 += wk * __half2float(p[dw0 + 3]);
        }
        float4 q; q.x = v0; q.y = v1; q.z = v2; q.w = v3;
        *(float4*)&dst[r * 104 + c4] = q;
    }
    __syncthreads();
    for (int i = tid; i < 1024; i += 256) {
        int wl = i & 31, hl = i >> 5;
        int base = hl * 104 + wl * 3;
        float e = 0.f;
        #pragma unroll
        for (int c = 0; c < 3; ++c) {
            float conv = 0.f;
            #pragma unroll
            for (int dh = 0; dh < 3; ++dh)
                #pragma unroll
                for (int dw = 0; dw < 3; ++dw)
                    conv += kn[(dh * 3 + dw) * 3 + c] * dst[base + dh * 104 + dw * 3 + c];
            e += dst[base + 104 + 3 + c] - conv;
        }
        es[b * (TH * TW) + (ohb + hl) * TW + owb + wl] = e;
    }
}

__global__ void levels_kernel(const __half* __restrict__ xh2, const __half* __restrict__ xh4,
                              const __half* __restrict__ xh8, const float* __restrict__ knorm,
                              float* __restrict__ es2, float* __restrict__ es3,
                              float* __restrict__ es4, int block_base) {
    __shared__ __align__(16) float smem[4224];
    int vb = blockIdx.x + block_base;
    if (vb < 2048) {
        level_body<2>(xh2, knorm, 1, es2, vb & 7, (vb >> 3) & 7, vb >> 6, smem);
    } else if (vb < 2560) {
        int l = vb - 2048;
        level_body<4>(xh4, knorm, 2, es3, l & 3, (l >> 2) & 3, l >> 4, smem);
    } else {
        int l = vb - 2560;
        level_body<8>(xh8, knorm, 3, es4, l & 1, (l >> 1) & 1, l >> 2, smem);
    }
}

// ---------------- fused: level-1 residual + 3 upsampled levels, square, reduce ----------------
__global__ void fused_kernel(const float* __restrict__ x, const float* __restrict__ knorm,
                             const float* __restrict__ es2, const float* __restrict__ es3,
                             const float* __restrict__ es4, double* __restrict__ partials) {
    __shared__ __align__(16) float xt[34 * 104];
    __shared__ float e2t[18 * 18];
    __shared__ float e3t[10 * 10];
    __shared__ float e4t[6 * 6];
    __shared__ float kn[27];
    __shared__ float smf[4];
    int b = blockIdx.z;
    int hb = blockIdx.y * 32, wb = blockIdx.x * 32;
    int tid = threadIdx.x;
    if (tid < 27) kn[tid] = knorm[tid];
    int xoff = b * (HH * WW * CC);
    int dwb = wb * 3 - 3;
    for (int i = tid; i < 34 * 32; i += 256) {
        int r = i >> 5, c4 = (i & 31) * 4;
        if (c4 >= 102) continue;
        int gh = hb - 1 + r;
        bool ghv = (unsigned)gh < (unsigned)HH;
        int gbase = xoff + gh * (WW * CC);
        int dw0 = dwb + c4;
        float4 v;
        v.x = (ghv && (unsigned)(dw0 + 0) < (unsigned)(WW * CC)) ? x[gbase + dw0 + 0] : 0.f;
        v.y = (ghv && (unsigned)(dw0 + 1) < (unsigned)(WW * CC)) ? x[gbase + dw0 + 1] : 0.f;
        v.z = (ghv && (unsigned)(dw0 + 2) < (unsigned)(WW * CC)) ? x[gbase + dw0 + 2] : 0.f;
        v.w = (ghv && (unsigned)(dw0 + 3) < (unsigned)(WW * CC)) ? x[gbase + dw0 + 3] : 0.f;
        *(float4*)&xt[r * 104 + c4] = v;
    }
    {
        const float* e2b = es2 + b * (256 * 256);
        int h0 = hb / 2 - 1, w0 = wb / 2 - 1;
        for (int i = tid; i < 18 * 32; i += 256) {
            int r = i >> 5, c = i & 31;
            if (c < 18) {
                int gh = iclamp_(h0 + r, 0, 255);
                int gw = iclamp_(w0 + c, 0, 255);
                e2t[r * 18 + c] = e2b[gh * 256 + gw];
            }
        }
        const float* e3b = es3 + b * (128 * 128);
        int h03 = hb / 4 - 1, w03 = wb / 4 - 1;
        if (tid < 160) {
            int r = tid >> 4, c = tid & 15;
            if (c < 10) {
                int gh = iclamp_(h03 + r, 0, 127);
                int gw = iclamp_(w03 + c, 0, 127);
                e3t[r * 10 + c] = e3b[gh * 128 + gw];
            }
        }
        const float* e4b = es4 + b * (64 * 64);
        int h04 = hb / 8 - 1, w04 = wb / 8 - 1;
        if (tid < 48) {
            int r = tid >> 3, c = tid & 7;
            if (c < 6) {
                int gh = iclamp_(h04 + r, 0, 63);
                int gw = iclamp_(w04 + c, 0, 63);
                e4t[r * 6 + c] = e4b[gh * 64 + gw];
            }
        }
    }
    __syncthreads();

    int wl = tid & 31, q = tid >> 5;
    // horizontal bilinear params (shared by all 4 rows this thread owns)
    int m2 = wl & 1;  float fw2 = m2 ? 0.25f : 0.75f;              int rw2 = (wl >> 1) + m2;
    int m4 = wl & 3;  float fw4 = ((m4 + 2) & 3) * 0.25f + 0.125f; int rw4 = (wl >> 2) + (m4 < 2 ? 0 : 1);
    int m8 = wl & 7;  float fw8 = ((m8 + 4) & 7) * 0.125f + 0.0625f; int rw8 = (wl >> 3) + (m8 < 4 ? 0 : 1);
    // vertical params for row q (rows q+8k shift indices by 4k/2k/k)
    int n2 = q & 1;   float fh2 = n2 ? 0.25f : 0.75f;              int rh2b = (q >> 1) + n2;
    int n4 = q & 3;   float fh4 = ((n4 + 2) & 3) * 0.25f + 0.125f; int rh4b = (q >> 2) + (n4 < 2 ? 0 : 1);
    float fh8 = ((q + 4) & 7) * 0.125f + 0.0625f;                  int rh8b = (q < 4 ? 0 : 1);

    float acc = 0.f;
    #pragma unroll
    for (int k = 0; k < 4; ++k) {
        int hl = q + 8 * k;
        int base = hl * 104 + wl * 3;
        float e = 0.f;
        #pragma unroll
        for (int c = 0; c < 3; ++c) {
            float conv = 0.f;
            #pragma unroll
            for (int dh = 0; dh < 3; ++dh)
                #pragma unroll
                for (int dw = 0; dw < 3; ++dw)
                    conv += kn[(dh * 3 + dw) * 3 + c] * xt[base + dh * 104 + dw * 3 + c];
            e += xt[base + 104 + 3 + c] - conv;
        }
        {
            int rh = rh2b + 4 * k;
            float v00 = e2t[rh * 18 + rw2], v01 = e2t[rh * 18 + rw2 + 1];
            float v10 = e2t[rh * 18 + 18 + rw2], v11 = e2t[rh * 18 + 18 + rw2 + 1];
            float top = v00 + fw2 * (v01 - v00);
            float bot = v10 + fw2 * (v11 - v10);
            e += top + fh2 * (bot - top);
        }
        {
            int rh = rh4b + 2 * k;
            float v00 = e3t[rh * 10 + rw4], v01 = e3t[rh * 10 + rw4 + 1];
            float v10 = e3t[rh * 10 + 10 + rw4], v11 = e3t[rh * 10 + 10 + rw4 + 1];
            float top = v00 + fw4 * (v01 - v00);
            float bot = v10 + fw4 * (v11 - v10);
            e += top + fh4 * (bot - top);
        }
        {
            int rh = rh8b + k;
            float v00 = e4t[rh * 6 + rw8], v01 = e4t[rh * 6 + rw8 + 1];
            float v10 = e4t[rh * 6 + 6 + rw8], v11 = e4t[rh * 6 + 6 + rw8 + 1];
            float top = v00 + fw8 * (v01 - v00);
            float bot = v10 + fw8 * (v11 - v10);
            e += top + fh8 * (bot - top);
        }
        acc += e * e;
    }
    #pragma unroll
    for (int off = 32; off; off >>= 1) acc += __shfl_down(acc, off);
    if ((tid & 63) == 0) smf[tid >> 6] = acc;
    __syncthreads();
    if (tid == 0) {
        double s = (double)smf[0] + (double)smf[1] + (double)smf[2] + (double)smf[3];
        partials[(b * 16 + blockIdx.y) * 16 + blockIdx.x] = s;
    }
}

__global__ void final_kernel(const double* __restrict__ partials, int n,
                             const double* __restrict__ kl, float* __restrict__ out) {
    __shared__ double sm[256];
    double acc = 0.0;
    for (int i = threadIdx.x; i < n; i += blockDim.x) acc += partials[i];
    sm[threadIdx.x] = acc;
    __syncthreads();
    for (int s = 128; s > 0; s >>= 1) {
        if (threadIdx.x < (unsigned)s) sm[threadIdx.x] += sm[threadIdx.x + s];
        __syncthreads();
    }
    if (threadIdx.x == 0) out[0] = (float)(sm[0] / (double)BB + (double)LL * kl[0]);
}

extern "C" void kernel_launch(void* const* d_in, const int* in_sizes, int n_in,
                              void* d_out, int out_size, void* d_ws, size_t ws_size,
                              hipStream_t stream) {
    const float* x = (const float*)d_in[0];
    const float* loc = (const float*)d_in[1];
    const float* scale = (const float*)d_in[2];
    const float* eps = (const float*)d_in[3];
    float* out = (float*)d_out;

    char* ws = (char*)d_ws;
    float* knorm = (float*)(ws + 0);
    double* kl = (double*)(ws + 512);
    double* partials = (double*)(ws + 1024);          // 8192*8 = 65536 -> 66560
    float* es4 = (float*)(ws + 131072);               // 524288  -> 655360
    float* es3 = (float*)(ws + 655360);               // 2097152 -> 2752512
    float* es2 = (float*)(ws + 2752512);              // 8388608 -> 11141120
    (void)in_sizes; (void)n_in; (void)out_size;

    prep_kernel<<<1, 64, 0, stream>>>(loc, scale, eps, knorm, kl);

    const size_t SINGLE_NEED = 55181312ull;
    if (ws_size >= SINGLE_NEED) {
        __half* xh2 = (__half*)(ws + 11141120);       // 25165824 -> 36306944
        __half* xh4 = (__half*)(ws + 36306944);       // 12582912 -> 48889856
        __half* xh8 = (__half*)(ws + 48889856);       // 6291456  -> 55181312
        hpass_kernel<<<BB * HH, 256, 0, stream>>>(x, xh2, xh4, xh8);
        levels_kernel<<<2688, 256, 0, stream>>>(xh2, xh4, xh8, knorm, es2, es3, es4, 0);
    } else {
        // split path: xh4+xh8 first, then xh2 reuses the same region (<= 36.3 MB peak)
        __half* xh4 = (__half*)(ws + 11141120);       // 12582912 -> 23724032
        __half* xh8 = (__half*)(ws + 23724032);       // 6291456  -> 30015488
        __half* xh2 = (__half*)(ws + 11141120);       // 25165824 -> 36306944
        hpass_kernel<<<BB * HH, 256, 0, stream>>>(x, nullptr, xh4, xh8);
        levels_kernel<<<640, 256, 0, stream>>>(nullptr, xh4, xh8, knorm, es2, es3, es4, 2048);
        hpass_kernel<<<BB * HH, 256, 0, stream>>>(x, xh2, nullptr, nullptr);
        levels_kernel<<<2048, 256, 0, stream>>>(xh2, nullptr, nullptr, knorm, es2, es3, es4, 0);
    }

    fused_kernel<<<dim3(16, 16, BB), 256, 0, stream>>>(x, knorm, es2, es3, es4, partials);
    final_kernel<<<1, 256, 0, stream>>>(partials, 8192, kl, out);
}

// Round 4
// 151.563 us; speedup vs baseline: 3.1887x; 1.2173x over previous
//
#include <hip/hip_runtime.h>
#include <hip/hip_fp16.h>
#include <math.h>

#define BB 32
#define HH 512
#define WW 512
#define CC 3
#define LL 4

static __device__ __forceinline__ float softplusf_(float x) {
    if (x > 20.f) return x;
    return log1pf(expf(x));
}
static __device__ __forceinline__ int iclamp_(int v, int lo, int hi) {
    return v < lo ? lo : (v > hi ? hi : v);
}

// ---------------- prep: normalized per-level kernels + KL ----------------
__global__ void prep_kernel(const float* __restrict__ loc, const float* __restrict__ scale,
                            const float* __restrict__ eps, float* __restrict__ knorm,
                            double* __restrict__ kl_out) {
    int tid = threadIdx.x;   // 64 threads
    float klv = 0.f;
    if (tid < 27) {
        float s = softplusf_(scale[tid]);
        float m = loc[tid];
        klv = -logf(s) + 0.5f * (s * s + m * m) - 0.5f;
    }
    #pragma unroll
    for (int off = 32; off; off >>= 1) klv += __shfl_down(klv, off);
    if (tid == 0) *kl_out = (double)klv;
    if (tid < 12) {
        int l = tid / 3;
        int c = tid - l * 3;
        float v[9];
        float sum = 0.f;
        #pragma unroll
        for (int t = 0; t < 9; ++t) {
            int idx = t * 3 + c;
            float s = softplusf_(scale[idx]);
            float val = loc[idx] + s * eps[l * 27 + idx];
            if (t == 4) val = 0.f;
            v[t] = val;
            sum += val;
        }
        float denom = sum + 1e-7f;
        #pragma unroll
        for (int t = 0; t < 9; ++t)
            knorm[l * 27 + t * 3 + c] = v[t] / denom;
    }
}

// ---------------- single-read horizontal downsample: xh2, xh4, xh8 ----------------
__global__ void hpass_kernel(const float* __restrict__ x, __half* __restrict__ xh2,
                             __half* __restrict__ xh4, __half* __restrict__ xh8) {
    __shared__ __align__(16) float row[WW * CC];
    int bh = blockIdx.x;                       // b*512 + h
    int tid = threadIdx.x;
    const float4* src = (const float4*)(x + bh * (WW * CC));
    float4* dstv = (float4*)row;
    for (int i = tid; i < WW * CC / 4; i += 256) dstv[i] = src[i];
    __syncthreads();

    if (xh2) {                                  // F=2: all 256 threads
        int ow = tid;
        float sfw = 2.f * ow + 0.5f;
        int j0 = 2 * ow - 1;
        float wv[4]; float s = 0.f;
        #pragma unroll
        for (int k = 0; k < 4; ++k) {
            int j = j0 + k;
            float w = (j >= 0 && j < WW) ? (1.f - fabsf(j - sfw) * 0.5f) : 0.f;
            wv[k] = w; s += w;
        }
        float inv = 1.f / s;
        float a0 = 0, a1 = 0, a2 = 0;
        #pragma unroll
        for (int k = 0; k < 4; ++k) {
            int j = iclamp_(j0 + k, 0, WW - 1);
            float w = wv[k] * inv;
            a0 += w * row[j * 3 + 0];
            a1 += w * row[j * 3 + 1];
            a2 += w * row[j * 3 + 2];
        }
        __half* o = xh2 + bh * 768 + ow * 3;
        o[0] = __float2half_rn(a0); o[1] = __float2half_rn(a1); o[2] = __float2half_rn(a2);
    }
    if (xh4 && tid >= 64 && tid < 192) {        // F=4
        int ow = tid - 64;
        float sfw = 4.f * ow + 1.5f;
        int j0 = 4 * ow - 2;
        float wv[8]; float s = 0.f;
        #pragma unroll
        for (int k = 0; k < 8; ++k) {
            int j = j0 + k;
            float w = (j >= 0 && j < WW) ? (1.f - fabsf(j - sfw) * 0.25f) : 0.f;
            wv[k] = w; s += w;
        }
        float inv = 1.f / s;
        float a0 = 0, a1 = 0, a2 = 0;
        #pragma unroll
        for (int k = 0; k < 8; ++k) {
            int j = iclamp_(j0 + k, 0, WW - 1);
            float w = wv[k] * inv;
            a0 += w * row[j * 3 + 0];
            a1 += w * row[j * 3 + 1];
            a2 += w * row[j * 3 + 2];
        }
        __half* o = xh4 + bh * 384 + ow * 3;
        o[0] = __float2half_rn(a0); o[1] = __float2half_rn(a1); o[2] = __float2half_rn(a2);
    }
    if (xh8 && tid >= 192) {                    // F=8
        int ow = tid - 192;
        float sfw = 8.f * ow + 3.5f;
        int j0 = 8 * ow - 4;
        float wv[16]; float s = 0.f;
        #pragma unroll
        for (int k = 0; k < 16; ++k) {
            int j = j0 + k;
            float w = (j >= 0 && j < WW) ? (1.f - fabsf(j - sfw) * 0.125f) : 0.f;
            wv[k] = w; s += w;
        }
        float inv = 1.f / s;
        float a0 = 0, a1 = 0, a2 = 0;
        #pragma unroll
        for (int k = 0; k < 16; ++k) {
            int j = iclamp_(j0 + k, 0, WW - 1);
            float w = wv[k] * inv;
            a0 += w * row[j * 3 + 0];
            a1 += w * row[j * 3 + 1];
            a2 += w * row[j * 3 + 2];
        }
        __half* o = xh8 + bh * 192 + ow * 3;
        o[0] = __float2half_rn(a0); o[1] = __float2half_rn(a1); o[2] = __float2half_rn(a2);
    }
}

// ---------------- per-level: LDS-staged vertical pass + conv + channel-sum ----------------
// Output tile: THB rows x 32 cols. Stage rows RS = (THB+3)*F of 108 halves.
template <int F, int THB>
static __device__ __forceinline__ void level_body(const __half* __restrict__ xh,
                                                  const float* __restrict__ knorm_all, int lvl,
                                                  float* __restrict__ es, int bx, int by, int b,
                                                  char* smem_raw) {
    constexpr int TH = HH / F, TW = WW / F, TW3 = TW * 3, TAPS = 2 * F;
    constexpr int RS = (THB + 3) * F;     // staged input rows
    constexpr int DR = THB + 2;           // ds rows incl conv halo
    __half* stg = (__half*)smem_raw;                          // [RS][108]
    float* dst = (float*)(smem_raw + RS * 108 * 2);           // [DR][104]
    float* wv = dst + DR * 104;                               // [DR][TAPS]
    float* kn = wv + DR * TAPS;                               // [27]
    int owb = bx * 32, ohb = by * THB;
    int tid = threadIdx.x;
    if (tid < 27) kn[tid] = knorm_all[lvl * 27 + tid];
    if (tid >= 32 && tid < 32 + DR) {
        int r = tid - 32;
        int oh = ohb - 1 + r;
        if (oh < 0 || oh >= TH) {
            #pragma unroll
            for (int k = 0; k < TAPS; ++k) wv[r * TAPS + k] = 0.f;
        } else {
            float sfh = (oh + 0.5f) * F - 0.5f;
            int j0 = oh * F - F / 2;
            float tmp[TAPS]; float s = 0.f;
            #pragma unroll
            for (int k = 0; k < TAPS; ++k) {
                int j = j0 + k;
                float w = (j >= 0 && j < HH) ? (1.f - fabsf(j - sfh) * (1.0f / F)) : 0.f;
                tmp[k] = w; s += w;
            }
            float inv = 1.f / s;
            #pragma unroll
            for (int k = 0; k < TAPS; ++k) wv[r * TAPS + k] = tmp[k] * inv;
        }
    }
    // stage xh tile (coalesced ushort4 where fully in-bounds)
    int jmin = (ohb - 1) * F - F / 2;
    int cb = owb * 3 - 4;                 // aligned stage base (covers halo col at cb+1)
    bool fast = (cb >= 0) && (cb + 108 <= TW3);
    const __half* xb = xh + b * (HH * TW3);
    for (int i = tid; i < RS * 27; i += 256) {
        int r = i / 27;
        int c4 = (i - r * 27) * 4;
        int jh = iclamp_(jmin + r, 0, HH - 1);
        const __half* rp = xb + jh * TW3;
        if (fast) {
            *(ushort4*)&stg[r * 108 + c4] = *(const ushort4*)(rp + cb + c4);
        } else {
            #pragma unroll
            for (int u = 0; u < 4; ++u) {
                int col = iclamp_(cb + c4 + u, 0, TW3 - 1);
                stg[r * 108 + c4 + u] = rp[col];
            }
        }
    }
    __syncthreads();
    // vertical pass from LDS: dst[r][jc] = sum_k wv[r][k] * stg[r*F+k][jc+1]
    int dwb = owb * 3 - 3;
    for (int i = tid; i < DR * 26; i += 256) {
        int r = i / 26;
        int c4 = (i - r * 26) * 4;
        const float* wr = &wv[r * TAPS];
        const __half* sp0 = &stg[r * F * 108 + c4 + 1];
        float v0 = 0, v1 = 0, v2 = 0, v3 = 0;
        #pragma unroll
        for (int k = 0; k < TAPS; ++k) {
            float wk = wr[k];
            const __half* sp = sp0 + k * 108;
            v0 += wk * __half2float(sp[0]);
            v1 += wk * __half2float(sp[1]);
            v2 += wk * __half2float(sp[2]);
            v3 += wk * __half2float(sp[3]);
        }
        int dw0 = dwb + c4;
        if ((unsigned)(dw0 + 0) >= (unsigned)TW3) v0 = 0.f;
        if ((unsigned)(dw0 + 1) >= (unsigned)TW3) v1 = 0.f;
        if ((unsigned)(dw0 + 2) >= (unsigned)TW3) v2 = 0.f;
        if ((unsigned)(dw0 + 3) >= (unsigned)TW3) v3 = 0.f;
        float4 q; q.x = v0; q.y = v1; q.z = v2; q.w = v3;
        *(float4*)&dst[r * 104 + c4] = q;
    }
    __syncthreads();
    // conv + channel-sum + write
    for (int i = tid; i < THB * 32; i += 256) {
        int wl = i & 31, hl = i >> 5;
        int base = hl * 104 + wl * 3;
        float e = 0.f;
        #pragma unroll
        for (int c = 0; c < 3; ++c) {
            float conv = 0.f;
            #pragma unroll
            for (int dh = 0; dh < 3; ++dh)
                #pragma unroll
                for (int dw = 0; dw < 3; ++dw)
                    conv += kn[(dh * 3 + dw) * 3 + c] * dst[base + dh * 104 + dw * 3 + c];
            e += dst[base + 104 + 3 + c] - conv;
        }
        es[b * (TH * TW) + (ohb + hl) * TW + owb + wl] = e;
    }
}

// block layout: [0,4096)=L2 (8x16x32), [4096,6144)=L4 (4x16x32), [6144,7168)=L8 (2x16x32)
__global__ void levels_kernel(const __half* __restrict__ xh2, const __half* __restrict__ xh4,
                              const __half* __restrict__ xh8, const float* __restrict__ knorm,
                              float* __restrict__ es2, float* __restrict__ es3,
                              float* __restrict__ es4, int block_base) {
    __shared__ __align__(16) char smem[16192];
    int vb = blockIdx.x + block_base;
    if (vb < 4096) {
        level_body<2, 16>(xh2, knorm, 1, es2, vb & 7, (vb >> 3) & 15, vb >> 7, smem);
    } else if (vb < 6144) {
        int l = vb - 4096;
        level_body<4, 8>(xh4, knorm, 2, es3, l & 3, (l >> 2) & 15, l >> 6, smem);
    } else {
        int l = vb - 6144;
        level_body<8, 4>(xh8, knorm, 3, es4, l & 1, (l >> 1) & 15, l >> 5, smem);
    }
}

// ---------------- fused: level-1 residual + 3 upsampled levels, square, reduce ----------------
__global__ void fused_kernel(const float* __restrict__ x, const float* __restrict__ knorm,
                             const float* __restrict__ es2, const float* __restrict__ es3,
                             const float* __restrict__ es4, double* __restrict__ partials) {
    __shared__ __align__(16) float xt[34 * 104];
    __shared__ float e2t[18 * 18];
    __shared__ float e3t[10 * 10];
    __shared__ float e4t[6 * 6];
    __shared__ float kn[27];
    __shared__ float smf[4];
    int b = blockIdx.z;
    int hb = blockIdx.y * 32, wb = blockIdx.x * 32;
    int tid = threadIdx.x;
    if (tid < 27) kn[tid] = knorm[tid];
    int xoff = b * (HH * WW * CC);
    int dwb = wb * 3 - 3;
    for (int i = tid; i < 34 * 32; i += 256) {
        int r = i >> 5, c4 = (i & 31) * 4;
        if (c4 >= 102) continue;
        int gh = hb - 1 + r;
        bool ghv = (unsigned)gh < (unsigned)HH;
        int gbase = xoff + gh * (WW * CC);
        int dw0 = dwb + c4;
        float4 v;
        v.x = (ghv && (unsigned)(dw0 + 0) < (unsigned)(WW * CC)) ? x[gbase + dw0 + 0] : 0.f;
        v.y = (ghv && (unsigned)(dw0 + 1) < (unsigned)(WW * CC)) ? x[gbase + dw0 + 1] : 0.f;
        v.z = (ghv && (unsigned)(dw0 + 2) < (unsigned)(WW * CC)) ? x[gbase + dw0 + 2] : 0.f;
        v.w = (ghv && (unsigned)(dw0 + 3) < (unsigned)(WW * CC)) ? x[gbase + dw0 + 3] : 0.f;
        *(float4*)&xt[r * 104 + c4] = v;
    }
    {
        const float* e2b = es2 + b * (256 * 256);
        int h0 = hb / 2 - 1, w0 = wb / 2 - 1;
        for (int i = tid; i < 18 * 32; i += 256) {
            int r = i >> 5, c = i & 31;
            if (c < 18) {
                int gh = iclamp_(h0 + r, 0, 255);
                int gw = iclamp_(w0 + c, 0, 255);
                e2t[r * 18 + c] = e2b[gh * 256 + gw];
            }
        }
        const float* e3b = es3 + b * (128 * 128);
        int h03 = hb / 4 - 1, w03 = wb / 4 - 1;
        if (tid < 160) {
            int r = tid >> 4, c = tid & 15;
            if (c < 10) {
                int gh = iclamp_(h03 + r, 0, 127);
                int gw = iclamp_(w03 + c, 0, 127);
                e3t[r * 10 + c] = e3b[gh * 128 + gw];
            }
        }
        const float* e4b = es4 + b * (64 * 64);
        int h04 = hb / 8 - 1, w04 = wb / 8 - 1;
        if (tid < 48) {
            int r = tid >> 3, c = tid & 7;
            if (c < 6) {
                int gh = iclamp_(h04 + r, 0, 63);
                int gw = iclamp_(w04 + c, 0, 63);
                e4t[r * 6 + c] = e4b[gh * 64 + gw];
            }
        }
    }
    __syncthreads();

    int wl = tid & 31, q = tid >> 5;
    int m2 = wl & 1;  float fw2 = m2 ? 0.25f : 0.75f;              int rw2 = (wl >> 1) + m2;
    int m4 = wl & 3;  float fw4 = ((m4 + 2) & 3) * 0.25f + 0.125f; int rw4 = (wl >> 2) + (m4 < 2 ? 0 : 1);
    int m8 = wl & 7;  float fw8 = ((m8 + 4) & 7) * 0.125f + 0.0625f; int rw8 = (wl >> 3) + (m8 < 4 ? 0 : 1);
    int n2 = q & 1;   float fh2 = n2 ? 0.25f : 0.75f;              int rh2b = (q >> 1) + n2;
    int n4 = q & 3;   float fh4 = ((n4 + 2) & 3) * 0.25f + 0.125f; int rh4b = (q >> 2) + (n4 < 2 ? 0 : 1);
    float fh8 = ((q + 4) & 7) * 0.125f + 0.0625f;                  int rh8b = (q < 4 ? 0 : 1);

    float acc = 0.f;
    #pragma unroll
    for (int k = 0; k < 4; ++k) {
        int hl = q + 8 * k;
        int base = hl * 104 + wl * 3;
        float e = 0.f;
        #pragma unroll
        for (int c = 0; c < 3; ++c) {
            float conv = 0.f;
            #pragma unroll
            for (int dh = 0; dh < 3; ++dh)
                #pragma unroll
                for (int dw = 0; dw < 3; ++dw)
                    conv += kn[(dh * 3 + dw) * 3 + c] * xt[base + dh * 104 + dw * 3 + c];
            e += xt[base + 104 + 3 + c] - conv;
        }
        {
            int rh = rh2b + 4 * k;
            float v00 = e2t[rh * 18 + rw2], v01 = e2t[rh * 18 + rw2 + 1];
            float v10 = e2t[rh * 18 + 18 + rw2], v11 = e2t[rh * 18 + 18 + rw2 + 1];
            float top = v00 + fw2 * (v01 - v00);
            float bot = v10 + fw2 * (v11 - v10);
            e += top + fh2 * (bot - top);
        }
        {
            int rh = rh4b + 2 * k;
            float v00 = e3t[rh * 10 + rw4], v01 = e3t[rh * 10 + rw4 + 1];
            float v10 = e3t[rh * 10 + 10 + rw4], v11 = e3t[rh * 10 + 10 + rw4 + 1];
            float top = v00 + fw4 * (v01 - v00);
            float bot = v10 + fw4 * (v11 - v10);
            e += top + fh4 * (bot - top);
        }
        {
            int rh = rh8b + k;
            float v00 = e4t[rh * 6 + rw8], v01 = e4t[rh * 6 + rw8 + 1];
            float v10 = e4t[rh * 6 + 6 + rw8], v11 = e4t[rh * 6 + 6 + rw8 + 1];
            float top = v00 + fw8 * (v01 - v00);
            float bot = v10 + fw8 * (v11 - v10);
            e += top + fh8 * (bot - top);
        }
        acc += e * e;
    }
    #pragma unroll
    for (int off = 32; off; off >>= 1) acc += __shfl_down(acc, off);
    if ((tid & 63) == 0) smf[tid >> 6] = acc;
    __syncthreads();
    if (tid == 0) {
        double s = (double)smf[0] + (double)smf[1] + (double)smf[2] + (double)smf[3];
        partials[(b * 16 + blockIdx.y) * 16 + blockIdx.x] = s;
    }
}

__global__ void final_kernel(const double* __restrict__ partials, int n,
                             const double* __restrict__ kl, float* __restrict__ out) {
    __shared__ double sm[256];
    double acc = 0.0;
    for (int i = threadIdx.x; i < n; i += blockDim.x) acc += partials[i];
    sm[threadIdx.x] = acc;
    __syncthreads();
    for (int s = 128; s > 0; s >>= 1) {
        if (threadIdx.x < (unsigned)s) sm[threadIdx.x] += sm[threadIdx.x + s];
        __syncthreads();
    }
    if (threadIdx.x == 0) out[0] = (float)(sm[0] / (double)BB + (double)LL * kl[0]);
}

extern "C" void kernel_launch(void* const* d_in, const int* in_sizes, int n_in,
                              void* d_out, int out_size, void* d_ws, size_t ws_size,
                              hipStream_t stream) {
    const float* x = (const float*)d_in[0];
    const float* loc = (const float*)d_in[1];
    const float* scale = (const float*)d_in[2];
    const float* eps = (const float*)d_in[3];
    float* out = (float*)d_out;

    char* ws = (char*)d_ws;
    float* knorm = (float*)(ws + 0);
    double* kl = (double*)(ws + 512);
    double* partials = (double*)(ws + 1024);          // 8192*8 -> ends 66560
    float* es4 = (float*)(ws + 131072);               // 524288  -> 655360
    float* es3 = (float*)(ws + 655360);               // 2097152 -> 2752512
    float* es2 = (float*)(ws + 2752512);              // 8388608 -> 11141120
    (void)in_sizes; (void)n_in; (void)out_size;

    prep_kernel<<<1, 64, 0, stream>>>(loc, scale, eps, knorm, kl);

    const size_t SINGLE_NEED = 55181312ull;
    if (ws_size >= SINGLE_NEED) {
        __half* xh2 = (__half*)(ws + 11141120);       // 25165824 -> 36306944
        __half* xh4 = (__half*)(ws + 36306944);       // 12582912 -> 48889856
        __half* xh8 = (__half*)(ws + 48889856);       // 6291456  -> 55181312
        hpass_kernel<<<BB * HH, 256, 0, stream>>>(x, xh2, xh4, xh8);
        levels_kernel<<<7168, 256, 0, stream>>>(xh2, xh4, xh8, knorm, es2, es3, es4, 0);
    } else {
        // split path: xh4+xh8 first, then xh2 reuses the same region (<= 36.3 MB peak)
        __half* xh4 = (__half*)(ws + 11141120);
        __half* xh8 = (__half*)(ws + 23724032);
        __half* xh2 = (__half*)(ws + 11141120);
        hpass_kernel<<<BB * HH, 256, 0, stream>>>(x, nullptr, xh4, xh8);
        levels_kernel<<<3072, 256, 0, stream>>>(nullptr, xh4, xh8, knorm, es2, es3, es4, 4096);
        hpass_kernel<<<BB * HH, 256, 0, stream>>>(x, xh2, nullptr, nullptr);
        levels_kernel<<<4096, 256, 0, stream>>>(xh2, nullptr, nullptr, knorm, es2, es3, es4, 0);
    }

    fused_kernel<<<dim3(16, 16, BB), 256, 0, stream>>>(x, knorm, es2, es3, es4, partials);
    final_kernel<<<1, 256, 0, stream>>>(partials, 8192, kl, out);
}

// Round 5
// 150.284 us; speedup vs baseline: 3.2158x; 1.0085x over previous
//
#include <hip/hip_runtime.h>
#include <hip/hip_fp16.h>
#include <math.h>

#define BB 32
#define HH 512
#define WW 512
#define CC 3
#define LL 4

static __device__ __forceinline__ float softplusf_(float x) {
    if (x > 20.f) return x;
    return log1pf(expf(x));
}
static __device__ __forceinline__ int iclamp_(int v, int lo, int hi) {
    return v < lo ? lo : (v > hi ? hi : v);
}

// ---------------- prep: normalized per-level kernels + KL ----------------
__global__ void prep_kernel(const float* __restrict__ loc, const float* __restrict__ scale,
                            const float* __restrict__ eps, float* __restrict__ knorm,
                            double* __restrict__ kl_out) {
    int tid = threadIdx.x;   // 64 threads
    float klv = 0.f;
    if (tid < 27) {
        float s = softplusf_(scale[tid]);
        float m = loc[tid];
        klv = -logf(s) + 0.5f * (s * s + m * m) - 0.5f;
    }
    #pragma unroll
    for (int off = 32; off; off >>= 1) klv += __shfl_down(klv, off);
    if (tid == 0) *kl_out = (double)klv;
    if (tid < 12) {
        int l = tid / 3;
        int c = tid - l * 3;
        float v[9];
        float sum = 0.f;
        #pragma unroll
        for (int t = 0; t < 9; ++t) {
            int idx = t * 3 + c;
            float s = softplusf_(scale[idx]);
            float val = loc[idx] + s * eps[l * 27 + idx];
            if (t == 4) val = 0.f;
            v[t] = val;
            sum += val;
        }
        float denom = sum + 1e-7f;
        #pragma unroll
        for (int t = 0; t < 9; ++t)
            knorm[l * 27 + t * 3 + c] = v[t] / denom;
    }
}

// ---------------- single-read horizontal downsample: xh2, xh4, xh8 ----------------
__global__ void hpass_kernel(const float* __restrict__ x, __half* __restrict__ xh2,
                             __half* __restrict__ xh4, __half* __restrict__ xh8) {
    __shared__ __align__(16) float row[WW * CC];
    __shared__ __align__(16) __half obuf[1344];   // 768 + 384 + 192
    int bh = blockIdx.x;                       // b*512 + h
    int tid = threadIdx.x;
    const float4* src = (const float4*)(x + bh * (WW * CC));
    float4* dstv = (float4*)row;
    for (int i = tid; i < WW * CC / 4; i += 256) dstv[i] = src[i];
    __syncthreads();

    if (xh2) {                                  // F=2: all 256 threads
        int ow = tid;
        float sfw = 2.f * ow + 0.5f;
        int j0 = 2 * ow - 1;
        float wv[4]; float s = 0.f;
        #pragma unroll
        for (int k = 0; k < 4; ++k) {
            int j = j0 + k;
            float w = (j >= 0 && j < WW) ? (1.f - fabsf(j - sfw) * 0.5f) : 0.f;
            wv[k] = w; s += w;
        }
        float inv = 1.f / s;
        float a0 = 0, a1 = 0, a2 = 0;
        #pragma unroll
        for (int k = 0; k < 4; ++k) {
            int j = iclamp_(j0 + k, 0, WW - 1);
            float w = wv[k] * inv;
            a0 += w * row[j * 3 + 0];
            a1 += w * row[j * 3 + 1];
            a2 += w * row[j * 3 + 2];
        }
        obuf[ow * 3 + 0] = __float2half_rn(a0);
        obuf[ow * 3 + 1] = __float2half_rn(a1);
        obuf[ow * 3 + 2] = __float2half_rn(a2);
    }
    if (xh4 && tid >= 64 && tid < 192) {        // F=4
        int ow = tid - 64;
        float sfw = 4.f * ow + 1.5f;
        int j0 = 4 * ow - 2;
        float wv[8]; float s = 0.f;
        #pragma unroll
        for (int k = 0; k < 8; ++k) {
            int j = j0 + k;
            float w = (j >= 0 && j < WW) ? (1.f - fabsf(j - sfw) * 0.25f) : 0.f;
            wv[k] = w; s += w;
        }
        float inv = 1.f / s;
        float a0 = 0, a1 = 0, a2 = 0;
        #pragma unroll
        for (int k = 0; k < 8; ++k) {
            int j = iclamp_(j0 + k, 0, WW - 1);
            float w = wv[k] * inv;
            a0 += w * row[j * 3 + 0];
            a1 += w * row[j * 3 + 1];
            a2 += w * row[j * 3 + 2];
        }
        obuf[768 + ow * 3 + 0] = __float2half_rn(a0);
        obuf[768 + ow * 3 + 1] = __float2half_rn(a1);
        obuf[768 + ow * 3 + 2] = __float2half_rn(a2);
    }
    if (xh8 && tid >= 192) {                    // F=8
        int ow = tid - 192;
        float sfw = 8.f * ow + 3.5f;
        int j0 = 8 * ow - 4;
        float wv[16]; float s = 0.f;
        #pragma unroll
        for (int k = 0; k < 16; ++k) {
            int j = j0 + k;
            float w = (j >= 0 && j < WW) ? (1.f - fabsf(j - sfw) * 0.125f) : 0.f;
            wv[k] = w; s += w;
        }
        float inv = 1.f / s;
        float a0 = 0, a1 = 0, a2 = 0;
        #pragma unroll
        for (int k = 0; k < 16; ++k) {
            int j = iclamp_(j0 + k, 0, WW - 1);
            float w = wv[k] * inv;
            a0 += w * row[j * 3 + 0];
            a1 += w * row[j * 3 + 1];
            a2 += w * row[j * 3 + 2];
        }
        obuf[1152 + ow * 3 + 0] = __float2half_rn(a0);
        obuf[1152 + ow * 3 + 1] = __float2half_rn(a1);
        obuf[1152 + ow * 3 + 2] = __float2half_rn(a2);
    }
    __syncthreads();
    // coalesced ushort4 stores
    if (xh2 && tid < 192) ((ushort4*)(xh2 + bh * 768))[tid] = ((const ushort4*)obuf)[tid];
    if (xh4 && tid < 96)  ((ushort4*)(xh4 + bh * 384))[tid] = ((const ushort4*)(obuf + 768))[tid];
    if (xh8 && tid < 24)  ((ushort4*)(xh8 + bh * 192))[tid] = ((const ushort4*)(obuf + 1152))[tid];
}

// ---------------- per-level: LDS-staged vertical pass + conv + channel-sum ----------------
// Output tile: THB rows x 32 cols. Stage rows RS = (THB+3)*F of 108 halves.
// dst shares the stage column window (108 wide, global float col = owb*3-4+j).
template <int F, int THB>
static __device__ __forceinline__ void level_body(const __half* __restrict__ xh,
                                                  const float* __restrict__ knorm_all, int lvl,
                                                  float* __restrict__ es, int bx, int by, int b,
                                                  char* smem_raw) {
    constexpr int TH = HH / F, TW = WW / F, TW3 = TW * 3, TAPS = 2 * F;
    constexpr int RS = (THB + 3) * F;     // staged input rows
    constexpr int DR = THB + 2;           // ds rows incl conv halo
    __half* stg = (__half*)smem_raw;                          // [RS][108]
    float* dst = (float*)(smem_raw + RS * 108 * 2);           // [DR][108]
    float* wv = dst + DR * 108;                               // [DR][TAPS]
    float* kn = wv + DR * TAPS;                               // [27]
    int owb = bx * 32, ohb = by * THB;
    int tid = threadIdx.x;
    if (tid < 27) kn[tid] = knorm_all[lvl * 27 + tid];
    if (tid >= 32 && tid < 32 + DR) {
        int r = tid - 32;
        int oh = ohb - 1 + r;
        if (oh < 0 || oh >= TH) {
            #pragma unroll
            for (int k = 0; k < TAPS; ++k) wv[r * TAPS + k] = 0.f;
        } else {
            float sfh = (oh + 0.5f) * F - 0.5f;
            int j0 = oh * F - F / 2;
            float tmp[TAPS]; float s = 0.f;
            #pragma unroll
            for (int k = 0; k < TAPS; ++k) {
                int j = j0 + k;
                float w = (j >= 0 && j < HH) ? (1.f - fabsf(j - sfh) * (1.0f / F)) : 0.f;
                tmp[k] = w; s += w;
            }
            float inv = 1.f / s;
            #pragma unroll
            for (int k = 0; k < TAPS; ++k) wv[r * TAPS + k] = tmp[k] * inv;
        }
    }
    // stage xh tile (coalesced ushort4 where fully in-bounds)
    int jmin = (ohb - 1) * F - F / 2;
    int cb = owb * 3 - 4;
    bool fast = (cb >= 0) && (cb + 108 <= TW3);
    const __half* xb = xh + b * (HH * TW3);
    for (int i = tid; i < RS * 27; i += 256) {
        int r = i / 27;
        int c4 = (i - r * 27) * 4;
        int jh = iclamp_(jmin + r, 0, HH - 1);
        const __half* rp = xb + jh * TW3;
        if (fast) {
            *(ushort4*)&stg[r * 108 + c4] = *(const ushort4*)(rp + cb + c4);
        } else {
            #pragma unroll
            for (int u = 0; u < 4; ++u) {
                int col = iclamp_(cb + c4 + u, 0, TW3 - 1);
                stg[r * 108 + c4 + u] = rp[col];
            }
        }
    }
    __syncthreads();
    // vertical pass: dst[r][j4..j4+3] = sum_k wv[r][k] * stg[r*F+k][j4..j4+3]
    for (int i = tid; i < DR * 27; i += 256) {
        int r = i / 27;
        int c4 = (i - r * 27) * 4;
        int gc = cb + c4;
        float v0 = 0, v1 = 0, v2 = 0, v3 = 0;
        if ((unsigned)gc < (unsigned)TW3) {       // whole chunk valid (both mult of 4)
            const __half* sp = &stg[r * F * 108 + c4];
            const float* wr = &wv[r * TAPS];
            #pragma unroll
            for (int k = 0; k < TAPS; ++k) {
                float wk = wr[k];
                const __half2* h2 = (const __half2*)(sp + k * 108);
                float2 f0 = __half22float2(h2[0]);
                float2 f1 = __half22float2(h2[1]);
                v0 += wk * f0.x; v1 += wk * f0.y;
                v2 += wk * f1.x; v3 += wk * f1.y;
            }
        }
        float4 q; q.x = v0; q.y = v1; q.z = v2; q.w = v3;
        *(float4*)&dst[r * 108 + c4] = q;
    }
    __syncthreads();
    // conv + channel-sum + write (conv base shifted +1 within the 108 window)
    for (int i = tid; i < THB * 32; i += 256) {
        int wl = i & 31, hl = i >> 5;
        int base = hl * 108 + wl * 3 + 1;
        float e = 0.f;
        #pragma unroll
        for (int c = 0; c < 3; ++c) {
            float conv = 0.f;
            #pragma unroll
            for (int dh = 0; dh < 3; ++dh)
                #pragma unroll
                for (int dw = 0; dw < 3; ++dw)
                    conv += kn[(dh * 3 + dw) * 3 + c] * dst[base + dh * 108 + dw * 3 + c];
            e += dst[base + 108 + 3 + c] - conv;
        }
        es[b * (TH * TW) + (ohb + hl) * TW + owb + wl] = e;
    }
}

// block layout: [0,4096)=L2 (8x16x32), [4096,6144)=L4 (4x16x32), [6144,7168)=L8 (2x16x32)
__global__ void levels_kernel(const __half* __restrict__ xh2, const __half* __restrict__ xh4,
                              const __half* __restrict__ xh8, const float* __restrict__ knorm,
                              float* __restrict__ es2, float* __restrict__ es3,
                              float* __restrict__ es4, int block_base) {
    __shared__ __align__(16) char smem[16896];
    int vb = blockIdx.x + block_base;
    if (vb < 4096) {
        level_body<2, 16>(xh2, knorm, 1, es2, vb & 7, (vb >> 3) & 15, vb >> 7, smem);
    } else if (vb < 6144) {
        int l = vb - 4096;
        level_body<4, 8>(xh4, knorm, 2, es3, l & 3, (l >> 2) & 15, l >> 6, smem);
    } else {
        int l = vb - 6144;
        level_body<8, 4>(xh8, knorm, 3, es4, l & 1, (l >> 1) & 15, l >> 5, smem);
    }
}

// ---------------- fused: level-1 residual + 3 upsampled levels, square, reduce ----------------
__global__ void __launch_bounds__(256, 4)
fused_kernel(const float* __restrict__ x, const float* __restrict__ knorm,
             const float* __restrict__ es2, const float* __restrict__ es3,
             const float* __restrict__ es4, double* __restrict__ partials) {
    __shared__ __align__(16) float xt[34 * 108];
    __shared__ float e2t[18 * 18];
    __shared__ float e3t[10 * 10];
    __shared__ float e4t[6 * 6];
    __shared__ float kn[27];
    __shared__ float smf[4];
    int b = blockIdx.z;
    int hb = blockIdx.y * 32, wb = blockIdx.x * 32;
    int tid = threadIdx.x;
    if (tid < 27) kn[tid] = knorm[tid];
    int xoff = b * (HH * WW * CC);
    int cb = wb * 3 - 4;
    bool fastc = (cb >= 0) && (cb + 108 <= WW * CC);
    for (int i = tid; i < 34 * 27; i += 256) {
        int r = i / 27;
        int c4 = (i - r * 27) * 4;
        int gh = hb - 1 + r;
        bool ghv = (unsigned)gh < (unsigned)HH;
        float4 v = {0.f, 0.f, 0.f, 0.f};
        if (ghv) {
            const float* rp = x + xoff + gh * (WW * CC);
            if (fastc) {
                v = *(const float4*)(rp + cb + c4);
            } else {
                int g0 = cb + c4;
                v.x = ((unsigned)(g0 + 0) < (unsigned)(WW * CC)) ? rp[g0 + 0] : 0.f;
                v.y = ((unsigned)(g0 + 1) < (unsigned)(WW * CC)) ? rp[g0 + 1] : 0.f;
                v.z = ((unsigned)(g0 + 2) < (unsigned)(WW * CC)) ? rp[g0 + 2] : 0.f;
                v.w = ((unsigned)(g0 + 3) < (unsigned)(WW * CC)) ? rp[g0 + 3] : 0.f;
            }
        }
        *(float4*)&xt[r * 108 + c4] = v;
    }
    {
        const float* e2b = es2 + b * (256 * 256);
        int h0 = hb / 2 - 1, w0 = wb / 2 - 1;
        for (int i = tid; i < 18 * 32; i += 256) {
            int r = i >> 5, c = i & 31;
            if (c < 18) {
                int gh = iclamp_(h0 + r, 0, 255);
                int gw = iclamp_(w0 + c, 0, 255);
                e2t[r * 18 + c] = e2b[gh * 256 + gw];
            }
        }
        const float* e3b = es3 + b * (128 * 128);
        int h03 = hb / 4 - 1, w03 = wb / 4 - 1;
        if (tid < 160) {
            int r = tid >> 4, c = tid & 15;
            if (c < 10) {
                int gh = iclamp_(h03 + r, 0, 127);
                int gw = iclamp_(w03 + c, 0, 127);
                e3t[r * 10 + c] = e3b[gh * 128 + gw];
            }
        }
        const float* e4b = es4 + b * (64 * 64);
        int h04 = hb / 8 - 1, w04 = wb / 8 - 1;
        if (tid < 48) {
            int r = tid >> 3, c = tid & 7;
            if (c < 6) {
                int gh = iclamp_(h04 + r, 0, 63);
                int gw = iclamp_(w04 + c, 0, 63);
                e4t[r * 6 + c] = e4b[gh * 64 + gw];
            }
        }
    }
    __syncthreads();

    int q = tid >> 3;        // output row 0..31
    int a = tid & 7;         // col group: cols 4a..4a+3
    // conv via register sliding window: window floats [12a .. 12a+19] per halo row
    float cv[4] = {0.f, 0.f, 0.f, 0.f};
    float cen[4] = {0.f, 0.f, 0.f, 0.f};
    #pragma unroll
    for (int dh = 0; dh < 3; ++dh) {
        float W[20];
        #pragma unroll
        for (int j = 0; j < 5; ++j) {
            float4 t = *(const float4*)&xt[(q + dh) * 108 + 12 * a + 4 * j];
            W[4 * j + 0] = t.x; W[4 * j + 1] = t.y; W[4 * j + 2] = t.z; W[4 * j + 3] = t.w;
        }
        #pragma unroll
        for (int p = 0; p < 4; ++p) {
            #pragma unroll
            for (int dw = 0; dw < 3; ++dw)
                #pragma unroll
                for (int c = 0; c < 3; ++c)
                    cv[p] += kn[(dh * 3 + dw) * 3 + c] * W[3 * p + 3 * dw + c + 1];
            if (dh == 1) cen[p] += W[3 * p + 4] + W[3 * p + 5] + W[3 * p + 6];
        }
    }
    float e[4];
    #pragma unroll
    for (int p = 0; p < 4; ++p) e[p] = cen[p] - cv[p];

    // bilinear adds (closed-form weights; verified formulas reparameterized to wl=4a+p)
    int n2 = q & 1;   float fh2 = n2 ? 0.25f : 0.75f;               int rh2 = (q >> 1) + n2;
    int n4 = q & 3;   float fh4 = ((n4 + 2) & 3) * 0.25f + 0.125f;  int rh4 = (q >> 2) + (n4 < 2 ? 0 : 1);
    int n8 = q & 7;   float fh8 = ((n8 + 4) & 7) * 0.125f + 0.0625f; int rh8 = (q >> 3) + (n8 < 4 ? 0 : 1);
    {   // L2: taps cols 2a..2a+3
        const float* r0 = &e2t[rh2 * 18 + 2 * a];
        const float* r1 = r0 + 18;
        float t0 = r0[0], t1 = r0[1], t2 = r0[2], t3 = r0[3];
        float b0 = r1[0], b1 = r1[1], b2 = r1[2], b3 = r1[3];
        float top, bot;
        top = t0 + 0.75f * (t1 - t0); bot = b0 + 0.75f * (b1 - b0); e[0] += top + fh2 * (bot - top);
        top = t1 + 0.25f * (t2 - t1); bot = b1 + 0.25f * (b2 - b1); e[1] += top + fh2 * (bot - top);
        top = t1 + 0.75f * (t2 - t1); bot = b1 + 0.75f * (b2 - b1); e[2] += top + fh2 * (bot - top);
        top = t2 + 0.25f * (t3 - t2); bot = b2 + 0.25f * (b3 - b2); e[3] += top + fh2 * (bot - top);
    }
    {   // L3: taps cols a..a+2
        const float* r0 = &e3t[rh4 * 10 + a];
        const float* r1 = r0 + 10;
        float t0 = r0[0], t1 = r0[1], t2 = r0[2];
        float b0 = r1[0], b1 = r1[1], b2 = r1[2];
        float top, bot;
        top = t0 + 0.625f * (t1 - t0); bot = b0 + 0.625f * (b1 - b0); e[0] += top + fh4 * (bot - top);
        top = t0 + 0.875f * (t1 - t0); bot = b0 + 0.875f * (b1 - b0); e[1] += top + fh4 * (bot - top);
        top = t1 + 0.125f * (t2 - t1); bot = b1 + 0.125f * (b2 - b1); e[2] += top + fh4 * (bot - top);
        top = t1 + 0.375f * (t2 - t1); bot = b1 + 0.375f * (b2 - b1); e[3] += top + fh4 * (bot - top);
    }
    {   // L4: one tap pair for all 4 px
        int rw8 = (a >> 1) + (a & 1);
        const float* r0 = &e4t[rh8 * 6 + rw8];
        const float* r1 = r0 + 6;
        float t0 = r0[0], t1 = r0[1];
        float b0 = r1[0], b1 = r1[1];
        float fwb = (a & 1) ? 0.0625f : 0.5625f;
        #pragma unroll
        for (int p = 0; p < 4; ++p) {
            float fw = fwb + 0.125f * p;
            float top = t0 + fw * (t1 - t0);
            float bot = b0 + fw * (b1 - b0);
            e[p] += top + fh8 * (bot - top);
        }
    }
    float acc = e[0] * e[0] + e[1] * e[1] + e[2] * e[2] + e[3] * e[3];
    #pragma unroll
    for (int off = 32; off; off >>= 1) acc += __shfl_down(acc, off);
    if ((tid & 63) == 0) smf[tid >> 6] = acc;
    __syncthreads();
    if (tid == 0) {
        double s = (double)smf[0] + (double)smf[1] + (double)smf[2] + (double)smf[3];
        partials[(b * 16 + blockIdx.y) * 16 + blockIdx.x] = s;
    }
}

__global__ void final_kernel(const double* __restrict__ partials, int n,
                             const double* __restrict__ kl, float* __restrict__ out) {
    __shared__ double sm[256];
    double acc = 0.0;
    for (int i = threadIdx.x; i < n; i += blockDim.x) acc += partials[i];
    sm[threadIdx.x] = acc;
    __syncthreads();
    for (int s = 128; s > 0; s >>= 1) {
        if (threadIdx.x < (unsigned)s) sm[threadIdx.x] += sm[threadIdx.x + s];
        __syncthreads();
    }
    if (threadIdx.x == 0) out[0] = (float)(sm[0] / (double)BB + (double)LL * kl[0]);
}

extern "C" void kernel_launch(void* const* d_in, const int* in_sizes, int n_in,
                              void* d_out, int out_size, void* d_ws, size_t ws_size,
                              hipStream_t stream) {
    const float* x = (const float*)d_in[0];
    const float* loc = (const float*)d_in[1];
    const float* scale = (const float*)d_in[2];
    const float* eps = (const float*)d_in[3];
    float* out = (float*)d_out;

    char* ws = (char*)d_ws;
    float* knorm = (float*)(ws + 0);
    double* kl = (double*)(ws + 512);
    double* partials = (double*)(ws + 1024);          // 8192*8 -> ends 66560
    float* es4 = (float*)(ws + 131072);               // 524288  -> 655360
    float* es3 = (float*)(ws + 655360);               // 2097152 -> 2752512
    float* es2 = (float*)(ws + 2752512);              // 8388608 -> 11141120
    (void)in_sizes; (void)n_in; (void)out_size;

    prep_kernel<<<1, 64, 0, stream>>>(loc, scale, eps, knorm, kl);

    const size_t SINGLE_NEED = 55181312ull;
    if (ws_size >= SINGLE_NEED) {
        __half* xh2 = (__half*)(ws + 11141120);       // 25165824 -> 36306944
        __half* xh4 = (__half*)(ws + 36306944);       // 12582912 -> 48889856
        __half* xh8 = (__half*)(ws + 48889856);       // 6291456  -> 55181312
        hpass_kernel<<<BB * HH, 256, 0, stream>>>(x, xh2, xh4, xh8);
        levels_kernel<<<7168, 256, 0, stream>>>(xh2, xh4, xh8, knorm, es2, es3, es4, 0);
    } else {
        // split path: xh4+xh8 first, then xh2 reuses the same region (<= 36.3 MB peak)
        __half* xh4 = (__half*)(ws + 11141120);
        __half* xh8 = (__half*)(ws + 23724032);
        __half* xh2 = (__half*)(ws + 11141120);
        hpass_kernel<<<BB * HH, 256, 0, stream>>>(x, nullptr, xh4, xh8);
        levels_kernel<<<3072, 256, 0, stream>>>(nullptr, xh4, xh8, knorm, es2, es3, es4, 4096);
        hpass_kernel<<<BB * HH, 256, 0, stream>>>(x, xh2, nullptr, nullptr);
        levels_kernel<<<4096, 256, 0, stream>>>(xh2, nullptr, nullptr, knorm, es2, es3, es4, 0);
    }

    fused_kernel<<<dim3(16, 16, BB), 256, 0, stream>>>(x, knorm, es2, es3, es4, partials);
    final_kernel<<<1, 256, 0, stream>>>(partials, 8192, kl, out);
}

// Round 6
// 122.758 us; speedup vs baseline: 3.9369x; 1.2242x over previous
//
#include <hip/hip_runtime.h>
#include <hip/hip_fp16.h>
#include <math.h>

#define BB 32
#define HH 512
#define WW 512
#define CC 3
#define LL 4

static __device__ __forceinline__ float softplusf_(float x) {
    if (x > 20.f) return x;
    return log1pf(expf(x));
}
static __device__ __forceinline__ int iclamp_(int v, int lo, int hi) {
    return v < lo ? lo : (v > hi ? hi : v);
}

// ---------------- prep: normalized per-level kernels + KL ----------------
__global__ void prep_kernel(const float* __restrict__ loc, const float* __restrict__ scale,
                            const float* __restrict__ eps, float* __restrict__ knorm,
                            double* __restrict__ kl_out) {
    int tid = threadIdx.x;   // 64 threads
    float klv = 0.f;
    if (tid < 27) {
        float s = softplusf_(scale[tid]);
        float m = loc[tid];
        klv = -logf(s) + 0.5f * (s * s + m * m) - 0.5f;
    }
    #pragma unroll
    for (int off = 32; off; off >>= 1) klv += __shfl_down(klv, off);
    if (tid == 0) *kl_out = (double)klv;
    if (tid < 12) {
        int l = tid / 3;
        int c = tid - l * 3;
        float v[9];
        float sum = 0.f;
        #pragma unroll
        for (int t = 0; t < 9; ++t) {
            int idx = t * 3 + c;
            float s = softplusf_(scale[idx]);
            float val = loc[idx] + s * eps[l * 27 + idx];
            if (t == 4) val = 0.f;
            v[t] = val;
            sum += val;
        }
        float denom = sum + 1e-7f;
        #pragma unroll
        for (int t = 0; t < 9; ++t)
            knorm[l * 27 + t * 3 + c] = v[t] / denom;
    }
}

// ---------------- horizontal downsample: wave-private, barrier-free ----------------
// 4 rows per block, one wave per row. Skewed LDS channel planes kill bank conflicts.
#define SJ(j) ((j) + ((j) >> 5))
#define PSTRIDE 532              // plane size in floats; 532%32=20 -> distinct base banks
#define RESC 1.1428571428571428f // 1/0.875: edge renorm (dropped tap mass is always 0.125)

__global__ void hpass_kernel(const float* __restrict__ x, __half* __restrict__ xh2,
                             __half* __restrict__ xh4, __half* __restrict__ xh8) {
    __shared__ __align__(16) float planes[4 * 3 * PSTRIDE];
    const int tid = threadIdx.x;
    const int lane = tid & 63;
    const int wv = tid >> 6;
    const int bh = blockIdx.x * 4 + wv;         // row id: b*512 + h
    float* pl = planes + wv * (3 * PSTRIDE);

    // stage this wave's row into 3 skewed channel planes (coalesced float4 reads)
    const float4* src = (const float4*)(x + bh * (WW * CC));
    #pragma unroll
    for (int s = 0; s < 6; ++s) {
        int i = lane + (s << 6);                // float4 index 0..383
        float4 v = src[i];
        int g = i << 2;
        int j = g / 3;
        int c = g - j * 3;
        float e[4] = {v.x, v.y, v.z, v.w};
        #pragma unroll
        for (int u = 0; u < 4; ++u) {
            pl[c * PSTRIDE + SJ(j)] = e[u];
            ++c;
            if (c == 3) { c = 0; ++j; }
        }
    }
    asm volatile("s_waitcnt lgkmcnt(0)" ::: "memory");   // wave-local LDS RAW fence

    if (xh2) {                                  // F=2: 4 outputs/lane
        const float W2k[4] = {0.125f, 0.375f, 0.375f, 0.125f};
        __half* o2 = xh2 + bh * 768;
        #pragma unroll
        for (int s = 0; s < 4; ++s) {
            int ow = lane + (s << 6);
            int j0 = 2 * ow - 1;
            bool edge = (j0 < 0) | (j0 + 3 > 511);
            float sc = edge ? RESC : 1.f;
            float wk[4]; int jj[4];
            #pragma unroll
            for (int k = 0; k < 4; ++k) {
                int j = j0 + k;
                wk[k] = (((unsigned)j < 512u) ? W2k[k] : 0.f) * sc;
                jj[k] = SJ(iclamp_(j, 0, 511));
            }
            #pragma unroll
            for (int c = 0; c < 3; ++c) {
                const float* p = pl + c * PSTRIDE;
                float a = 0.f;
                #pragma unroll
                for (int k = 0; k < 4; ++k) a += wk[k] * p[jj[k]];
                o2[ow * 3 + c] = __float2half_rn(a);
            }
        }
    }
    if (xh4) {                                  // F=4: 2 outputs/lane
        const float W4k[8] = {0.03125f, 0.09375f, 0.15625f, 0.21875f,
                              0.21875f, 0.15625f, 0.09375f, 0.03125f};
        __half* o4 = xh4 + bh * 384;
        #pragma unroll
        for (int s = 0; s < 2; ++s) {
            int ow = lane + (s << 6);
            int j0 = 4 * ow - 2;
            bool edge = (j0 < 0) | (j0 + 7 > 511);
            float sc = edge ? RESC : 1.f;
            float wk[8]; int jj[8];
            #pragma unroll
            for (int k = 0; k < 8; ++k) {
                int j = j0 + k;
                wk[k] = (((unsigned)j < 512u) ? W4k[k] : 0.f) * sc;
                jj[k] = SJ(iclamp_(j, 0, 511));
            }
            #pragma unroll
            for (int c = 0; c < 3; ++c) {
                const float* p = pl + c * PSTRIDE;
                float a = 0.f;
                #pragma unroll
                for (int k = 0; k < 8; ++k) a += wk[k] * p[jj[k]];
                o4[ow * 3 + c] = __float2half_rn(a);
            }
        }
    }
    if (xh8) {                                  // F=8: 1 output/lane
        const float W8k[16] = {0.0078125f, 0.0234375f, 0.0390625f, 0.0546875f,
                               0.0703125f, 0.0859375f, 0.1015625f, 0.1171875f,
                               0.1171875f, 0.1015625f, 0.0859375f, 0.0703125f,
                               0.0546875f, 0.0390625f, 0.0234375f, 0.0078125f};
        __half* o8 = xh8 + bh * 192;
        int ow = lane;
        int j0 = 8 * ow - 4;
        bool edge = (j0 < 0) | (j0 + 15 > 511);
        float sc = edge ? RESC : 1.f;
        float wk[16]; int jj[16];
        #pragma unroll
        for (int k = 0; k < 16; ++k) {
            int j = j0 + k;
            wk[k] = (((unsigned)j < 512u) ? W8k[k] : 0.f) * sc;
            jj[k] = SJ(iclamp_(j, 0, 511));
        }
        #pragma unroll
        for (int c = 0; c < 3; ++c) {
            const float* p = pl + c * PSTRIDE;
            float a = 0.f;
            #pragma unroll
            for (int k = 0; k < 16; ++k) a += wk[k] * p[jj[k]];
            o8[ow * 3 + c] = __float2half_rn(a);
        }
    }
}

// ---------------- per-level: LDS-staged vertical pass + conv + channel-sum ----------------
template <int F, int THB>
static __device__ __forceinline__ void level_body(const __half* __restrict__ xh,
                                                  const float* __restrict__ knorm_all, int lvl,
                                                  float* __restrict__ es, int bx, int by, int b,
                                                  char* smem_raw) {
    constexpr int TH = HH / F, TW = WW / F, TW3 = TW * 3, TAPS = 2 * F;
    constexpr int RS = (THB + 3) * F;     // staged input rows
    constexpr int DR = THB + 2;           // ds rows incl conv halo
    __half* stg = (__half*)smem_raw;                          // [RS][108]
    float* dst = (float*)(smem_raw + RS * 108 * 2);           // [DR][108]
    float* wvv = dst + DR * 108;                              // [DR][TAPS]
    float* kn = wvv + DR * TAPS;                              // [27]
    int owb = bx * 32, ohb = by * THB;
    int tid = threadIdx.x;
    if (tid < 27) kn[tid] = knorm_all[lvl * 27 + tid];
    if (tid >= 32 && tid < 32 + DR) {
        int r = tid - 32;
        int oh = ohb - 1 + r;
        if (oh < 0 || oh >= TH) {
            #pragma unroll
            for (int k = 0; k < TAPS; ++k) wvv[r * TAPS + k] = 0.f;
        } else {
            float sfh = (oh + 0.5f) * F - 0.5f;
            int j0 = oh * F - F / 2;
            float tmp[TAPS]; float s = 0.f;
            #pragma unroll
            for (int k = 0; k < TAPS; ++k) {
                int j = j0 + k;
                float w = (j >= 0 && j < HH) ? (1.f - fabsf(j - sfh) * (1.0f / F)) : 0.f;
                tmp[k] = w; s += w;
            }
            float inv = 1.f / s;
            #pragma unroll
            for (int k = 0; k < TAPS; ++k) wvv[r * TAPS + k] = tmp[k] * inv;
        }
    }
    int jmin = (ohb - 1) * F - F / 2;
    int cb = owb * 3 - 4;
    bool fast = (cb >= 0) && (cb + 108 <= TW3);
    const __half* xb = xh + b * (HH * TW3);
    for (int i = tid; i < RS * 27; i += 256) {
        int r = i / 27;
        int c4 = (i - r * 27) * 4;
        int jh = iclamp_(jmin + r, 0, HH - 1);
        const __half* rp = xb + jh * TW3;
        if (fast) {
            *(ushort4*)&stg[r * 108 + c4] = *(const ushort4*)(rp + cb + c4);
        } else {
            #pragma unroll
            for (int u = 0; u < 4; ++u) {
                int col = iclamp_(cb + c4 + u, 0, TW3 - 1);
                stg[r * 108 + c4 + u] = rp[col];
            }
        }
    }
    __syncthreads();
    for (int i = tid; i < DR * 27; i += 256) {
        int r = i / 27;
        int c4 = (i - r * 27) * 4;
        int gc = cb + c4;
        float v0 = 0, v1 = 0, v2 = 0, v3 = 0;
        if ((unsigned)gc < (unsigned)TW3) {
            const __half* sp = &stg[r * F * 108 + c4];
            const float* wr = &wvv[r * TAPS];
            #pragma unroll
            for (int k = 0; k < TAPS; ++k) {
                float wk = wr[k];
                const __half2* h2 = (const __half2*)(sp + k * 108);
                float2 f0 = __half22float2(h2[0]);
                float2 f1 = __half22float2(h2[1]);
                v0 += wk * f0.x; v1 += wk * f0.y;
                v2 += wk * f1.x; v3 += wk * f1.y;
            }
        }
        float4 q; q.x = v0; q.y = v1; q.z = v2; q.w = v3;
        *(float4*)&dst[r * 108 + c4] = q;
    }
    __syncthreads();
    for (int i = tid; i < THB * 32; i += 256) {
        int wl = i & 31, hl = i >> 5;
        int base = hl * 108 + wl * 3 + 1;
        float e = 0.f;
        #pragma unroll
        for (int c = 0; c < 3; ++c) {
            float conv = 0.f;
            #pragma unroll
            for (int dh = 0; dh < 3; ++dh)
                #pragma unroll
                for (int dw = 0; dw < 3; ++dw)
                    conv += kn[(dh * 3 + dw) * 3 + c] * dst[base + dh * 108 + dw * 3 + c];
            e += dst[base + 108 + 3 + c] - conv;
        }
        es[b * (TH * TW) + (ohb + hl) * TW + owb + wl] = e;
    }
}

// block layout: [0,4096)=L2 (8x16x32), [4096,6144)=L4 (4x16x32), [6144,7168)=L8 (2x16x32)
__global__ void levels_kernel(const __half* __restrict__ xh2, const __half* __restrict__ xh4,
                              const __half* __restrict__ xh8, const float* __restrict__ knorm,
                              float* __restrict__ es2, float* __restrict__ es3,
                              float* __restrict__ es4, int block_base) {
    __shared__ __align__(16) char smem[16896];
    int vb = blockIdx.x + block_base;
    if (vb < 4096) {
        level_body<2, 16>(xh2, knorm, 1, es2, vb & 7, (vb >> 3) & 15, vb >> 7, smem);
    } else if (vb < 6144) {
        int l = vb - 4096;
        level_body<4, 8>(xh4, knorm, 2, es3, l & 3, (l >> 2) & 15, l >> 6, smem);
    } else {
        int l = vb - 6144;
        level_body<8, 4>(xh8, knorm, 3, es4, l & 1, (l >> 1) & 15, l >> 5, smem);
    }
}

// ---------------- fused: level-1 residual + 3 upsampled levels, square, reduce ----------------
__global__ void __launch_bounds__(256, 8)
fused_kernel(const float* __restrict__ x, const float* __restrict__ knorm,
             const float* __restrict__ es2, const float* __restrict__ es3,
             const float* __restrict__ es4, double* __restrict__ partials) {
    __shared__ __align__(16) float xt[34 * 108];
    __shared__ float e2t[18 * 18];
    __shared__ float e3t[10 * 10];
    __shared__ float e4t[6 * 6];
    __shared__ float kn[27];
    __shared__ float smf[4];
    int b = blockIdx.z;
    int hb = blockIdx.y * 32, wb = blockIdx.x * 32;
    int tid = threadIdx.x;
    if (tid < 27) kn[tid] = knorm[tid];
    int xoff = b * (HH * WW * CC);
    int cb = wb * 3 - 4;
    bool fastc = (cb >= 0) && (cb + 108 <= WW * CC);
    for (int i = tid; i < 34 * 27; i += 256) {
        int r = i / 27;
        int c4 = (i - r * 27) * 4;
        int gh = hb - 1 + r;
        bool ghv = (unsigned)gh < (unsigned)HH;
        float4 v = {0.f, 0.f, 0.f, 0.f};
        if (ghv) {
            const float* rp = x + xoff + gh * (WW * CC);
            if (fastc) {
                v = *(const float4*)(rp + cb + c4);
            } else {
                int g0 = cb + c4;
                v.x = ((unsigned)(g0 + 0) < (unsigned)(WW * CC)) ? rp[g0 + 0] : 0.f;
                v.y = ((unsigned)(g0 + 1) < (unsigned)(WW * CC)) ? rp[g0 + 1] : 0.f;
                v.z = ((unsigned)(g0 + 2) < (unsigned)(WW * CC)) ? rp[g0 + 2] : 0.f;
                v.w = ((unsigned)(g0 + 3) < (unsigned)(WW * CC)) ? rp[g0 + 3] : 0.f;
            }
        }
        *(float4*)&xt[r * 108 + c4] = v;
    }
    {
        const float* e2b = es2 + b * (256 * 256);
        int h0 = hb / 2 - 1, w0 = wb / 2 - 1;
        for (int i = tid; i < 18 * 32; i += 256) {
            int r = i >> 5, c = i & 31;
            if (c < 18) {
                int gh = iclamp_(h0 + r, 0, 255);
                int gw = iclamp_(w0 + c, 0, 255);
                e2t[r * 18 + c] = e2b[gh * 256 + gw];
            }
        }
        const float* e3b = es3 + b * (128 * 128);
        int h03 = hb / 4 - 1, w03 = wb / 4 - 1;
        if (tid < 160) {
            int r = tid >> 4, c = tid & 15;
            if (c < 10) {
                int gh = iclamp_(h03 + r, 0, 127);
                int gw = iclamp_(w03 + c, 0, 127);
                e3t[r * 10 + c] = e3b[gh * 128 + gw];
            }
        }
        const float* e4b = es4 + b * (64 * 64);
        int h04 = hb / 8 - 1, w04 = wb / 8 - 1;
        if (tid < 48) {
            int r = tid >> 3, c = tid & 7;
            if (c < 6) {
                int gh = iclamp_(h04 + r, 0, 63);
                int gw = iclamp_(w04 + c, 0, 63);
                e4t[r * 6 + c] = e4b[gh * 64 + gw];
            }
        }
    }
    __syncthreads();

    int q = tid >> 3;        // output row 0..31
    int a = tid & 7;         // col group: cols 4a..4a+3
    float cv[4] = {0.f, 0.f, 0.f, 0.f};
    float cen[4] = {0.f, 0.f, 0.f, 0.f};
    #pragma unroll
    for (int dh = 0; dh < 3; ++dh) {
        float W[20];
        #pragma unroll
        for (int j = 0; j < 5; ++j) {
            float4 t = *(const float4*)&xt[(q + dh) * 108 + 12 * a + 4 * j];
            W[4 * j + 0] = t.x; W[4 * j + 1] = t.y; W[4 * j + 2] = t.z; W[4 * j + 3] = t.w;
        }
        #pragma unroll
        for (int p = 0; p < 4; ++p) {
            #pragma unroll
            for (int dw = 0; dw < 3; ++dw)
                #pragma unroll
                for (int c = 0; c < 3; ++c)
                    cv[p] += kn[(dh * 3 + dw) * 3 + c] * W[3 * p + 3 * dw + c + 1];
            if (dh == 1) cen[p] += W[3 * p + 4] + W[3 * p + 5] + W[3 * p + 6];
        }
    }
    float e[4];
    #pragma unroll
    for (int p = 0; p < 4; ++p) e[p] = cen[p] - cv[p];

    int n2 = q & 1;   float fh2 = n2 ? 0.25f : 0.75f;               int rh2 = (q >> 1) + n2;
    int n4 = q & 3;   float fh4 = ((n4 + 2) & 3) * 0.25f + 0.125f;  int rh4 = (q >> 2) + (n4 < 2 ? 0 : 1);
    int n8 = q & 7;   float fh8 = ((n8 + 4) & 7) * 0.125f + 0.0625f; int rh8 = (q >> 3) + (n8 < 4 ? 0 : 1);
    {   // L2: taps cols 2a..2a+3
        const float* r0 = &e2t[rh2 * 18 + 2 * a];
        const float* r1 = r0 + 18;
        float t0 = r0[0], t1 = r0[1], t2 = r0[2], t3 = r0[3];
        float b0 = r1[0], b1 = r1[1], b2 = r1[2], b3 = r1[3];
        float top, bot;
        top = t0 + 0.75f * (t1 - t0); bot = b0 + 0.75f * (b1 - b0); e[0] += top + fh2 * (bot - top);
        top = t1 + 0.25f * (t2 - t1); bot = b1 + 0.25f * (b2 - b1); e[1] += top + fh2 * (bot - top);
        top = t1 + 0.75f * (t2 - t1); bot = b1 + 0.75f * (b2 - b1); e[2] += top + fh2 * (bot - top);
        top = t2 + 0.25f * (t3 - t2); bot = b2 + 0.25f * (b3 - b2); e[3] += top + fh2 * (bot - top);
    }
    {   // L3: taps cols a..a+2
        const float* r0 = &e3t[rh4 * 10 + a];
        const float* r1 = r0 + 10;
        float t0 = r0[0], t1 = r0[1], t2 = r0[2];
        float b0 = r1[0], b1 = r1[1], b2 = r1[2];
        float top, bot;
        top = t0 + 0.625f * (t1 - t0); bot = b0 + 0.625f * (b1 - b0); e[0] += top + fh4 * (bot - top);
        top = t0 + 0.875f * (t1 - t0); bot = b0 + 0.875f * (b1 - b0); e[1] += top + fh4 * (bot - top);
        top = t1 + 0.125f * (t2 - t1); bot = b1 + 0.125f * (b2 - b1); e[2] += top + fh4 * (bot - top);
        top = t1 + 0.375f * (t2 - t1); bot = b1 + 0.375f * (b2 - b1); e[3] += top + fh4 * (bot - top);
    }
    {   // L4: one tap pair for all 4 px
        int rw8 = (a >> 1) + (a & 1);
        const float* r0 = &e4t[rh8 * 6 + rw8];
        const float* r1 = r0 + 6;
        float t0 = r0[0], t1 = r0[1];
        float b0 = r1[0], b1 = r1[1];
        float fwb = (a & 1) ? 0.0625f : 0.5625f;
        #pragma unroll
        for (int p = 0; p < 4; ++p) {
            float fw = fwb + 0.125f * p;
            float top = t0 + fw * (t1 - t0);
            float bot = b0 + fw * (b1 - b0);
            e[p] += top + fh8 * (bot - top);
        }
    }
    float acc = e[0] * e[0] + e[1] * e[1] + e[2] * e[2] + e[3] * e[3];
    #pragma unroll
    for (int off = 32; off; off >>= 1) acc += __shfl_down(acc, off);
    if ((tid & 63) == 0) smf[tid >> 6] = acc;
    __syncthreads();
    if (tid == 0) {
        double s = (double)smf[0] + (double)smf[1] + (double)smf[2] + (double)smf[3];
        partials[(b * 16 + blockIdx.y) * 16 + blockIdx.x] = s;
    }
}

__global__ void final_kernel(const double* __restrict__ partials, int n,
                             const double* __restrict__ kl, float* __restrict__ out) {
    __shared__ double sm[256];
    double acc = 0.0;
    for (int i = threadIdx.x; i < n; i += blockDim.x) acc += partials[i];
    sm[threadIdx.x] = acc;
    __syncthreads();
    for (int s = 128; s > 0; s >>= 1) {
        if (threadIdx.x < (unsigned)s) sm[threadIdx.x] += sm[threadIdx.x + s];
        __syncthreads();
    }
    if (threadIdx.x == 0) out[0] = (float)(sm[0] / (double)BB + (double)LL * kl[0]);
}

extern "C" void kernel_launch(void* const* d_in, const int* in_sizes, int n_in,
                              void* d_out, int out_size, void* d_ws, size_t ws_size,
                              hipStream_t stream) {
    const float* x = (const float*)d_in[0];
    const float* loc = (const float*)d_in[1];
    const float* scale = (const float*)d_in[2];
    const float* eps = (const float*)d_in[3];
    float* out = (float*)d_out;

    char* ws = (char*)d_ws;
    float* knorm = (float*)(ws + 0);
    double* kl = (double*)(ws + 512);
    double* partials = (double*)(ws + 1024);          // 8192*8 -> ends 66560
    float* es4 = (float*)(ws + 131072);               // 524288  -> 655360
    float* es3 = (float*)(ws + 655360);               // 2097152 -> 2752512
    float* es2 = (float*)(ws + 2752512);              // 8388608 -> 11141120
    (void)in_sizes; (void)n_in; (void)out_size;

    prep_kernel<<<1, 64, 0, stream>>>(loc, scale, eps, knorm, kl);

    const size_t SINGLE_NEED = 55181312ull;
    if (ws_size >= SINGLE_NEED) {
        __half* xh2 = (__half*)(ws + 11141120);       // 25165824 -> 36306944
        __half* xh4 = (__half*)(ws + 36306944);       // 12582912 -> 48889856
        __half* xh8 = (__half*)(ws + 48889856);       // 6291456  -> 55181312
        hpass_kernel<<<BB * HH / 4, 256, 0, stream>>>(x, xh2, xh4, xh8);
        levels_kernel<<<7168, 256, 0, stream>>>(xh2, xh4, xh8, knorm, es2, es3, es4, 0);
    } else {
        // split path: xh4+xh8 first, then xh2 reuses the same region (<= 36.3 MB peak)
        __half* xh4 = (__half*)(ws + 11141120);
        __half* xh8 = (__half*)(ws + 23724032);
        __half* xh2 = (__half*)(ws + 11141120);
        hpass_kernel<<<BB * HH / 4, 256, 0, stream>>>(x, nullptr, xh4, xh8);
        levels_kernel<<<3072, 256, 0, stream>>>(nullptr, xh4, xh8, knorm, es2, es3, es4, 4096);
        hpass_kernel<<<BB * HH / 4, 256, 0, stream>>>(x, xh2, nullptr, nullptr);
        levels_kernel<<<4096, 256, 0, stream>>>(xh2, nullptr, nullptr, knorm, es2, es3, es4, 0);
    }

    fused_kernel<<<dim3(16, 16, BB), 256, 0, stream>>>(x, knorm, es2, es3, es4, partials);
    final_kernel<<<1, 256, 0, stream>>>(partials, 8192, kl, out);
}

// Round 7
// 109.621 us; speedup vs baseline: 4.4087x; 1.1198x over previous
//
#include <hip/hip_runtime.h>
#include <hip/hip_fp16.h>
#include <math.h>

#define BB 32
#define HH 512
#define WW 512
#define CC 3
#define LL 4

static __device__ __forceinline__ float softplusf_(float x) {
    if (x > 20.f) return x;
    return log1pf(expf(x));
}
static __device__ __forceinline__ int iclamp_(int v, int lo, int hi) {
    return v < lo ? lo : (v > hi ? hi : v);
}

// ---------------- prep: normalized per-level kernels + KL ----------------
__global__ void prep_kernel(const float* __restrict__ loc, const float* __restrict__ scale,
                            const float* __restrict__ eps, float* __restrict__ knorm,
                            double* __restrict__ kl_out) {
    int tid = threadIdx.x;   // 64 threads
    float klv = 0.f;
    if (tid < 27) {
        float s = softplusf_(scale[tid]);
        float m = loc[tid];
        klv = -logf(s) + 0.5f * (s * s + m * m) - 0.5f;
    }
    #pragma unroll
    for (int off = 32; off; off >>= 1) klv += __shfl_down(klv, off);
    if (tid == 0) *kl_out = (double)klv;
    if (tid < 12) {
        int l = tid / 3;
        int c = tid - l * 3;
        float v[9];
        float sum = 0.f;
        #pragma unroll
        for (int t = 0; t < 9; ++t) {
            int idx = t * 3 + c;
            float s = softplusf_(scale[idx]);
            float val = loc[idx] + s * eps[l * 27 + idx];
            if (t == 4) val = 0.f;
            v[t] = val;
            sum += val;
        }
        float denom = sum + 1e-7f;
        #pragma unroll
        for (int t = 0; t < 9; ++t)
            knorm[l * 27 + t * 3 + c] = v[t] / denom;
    }
}

// ---------------- horizontal downsample: wave-private, barrier-free ----------------
#define SJ(j) ((j) + ((j) >> 5))
#define PSTRIDE 532
#define RESC 1.1428571428571428f

__global__ void hpass_kernel(const float* __restrict__ x, __half* __restrict__ xh2,
                             __half* __restrict__ xh4, __half* __restrict__ xh8) {
    __shared__ __align__(16) float planes[4 * 3 * PSTRIDE];
    const int tid = threadIdx.x;
    const int lane = tid & 63;
    const int wv = tid >> 6;
    const int bh = blockIdx.x * 4 + wv;         // row id: b*512 + h
    float* pl = planes + wv * (3 * PSTRIDE);

    const float4* src = (const float4*)(x + bh * (WW * CC));
    #pragma unroll
    for (int s = 0; s < 6; ++s) {
        int i = lane + (s << 6);                // float4 index 0..383
        float4 v = src[i];
        int g = i << 2;
        int j = g / 3;
        int c = g - j * 3;
        float e[4] = {v.x, v.y, v.z, v.w};
        #pragma unroll
        for (int u = 0; u < 4; ++u) {
            pl[c * PSTRIDE + SJ(j)] = e[u];
            ++c;
            if (c == 3) { c = 0; ++j; }
        }
    }
    asm volatile("s_waitcnt lgkmcnt(0)" ::: "memory");

    if (xh2) {                                  // F=2: 4 outputs/lane
        const float W2k[4] = {0.125f, 0.375f, 0.375f, 0.125f};
        __half* o2 = xh2 + bh * 768;
        #pragma unroll
        for (int s = 0; s < 4; ++s) {
            int ow = lane + (s << 6);
            int j0 = 2 * ow - 1;
            bool edge = (j0 < 0) | (j0 + 3 > 511);
            float sc = edge ? RESC : 1.f;
            float wk[4]; int jj[4];
            #pragma unroll
            for (int k = 0; k < 4; ++k) {
                int j = j0 + k;
                wk[k] = (((unsigned)j < 512u) ? W2k[k] : 0.f) * sc;
                jj[k] = SJ(iclamp_(j, 0, 511));
            }
            #pragma unroll
            for (int c = 0; c < 3; ++c) {
                const float* p = pl + c * PSTRIDE;
                float a = 0.f;
                #pragma unroll
                for (int k = 0; k < 4; ++k) a += wk[k] * p[jj[k]];
                o2[ow * 3 + c] = __float2half_rn(a);
            }
        }
    }
    if (xh4) {                                  // F=4: 2 outputs/lane
        const float W4k[8] = {0.03125f, 0.09375f, 0.15625f, 0.21875f,
                              0.21875f, 0.15625f, 0.09375f, 0.03125f};
        __half* o4 = xh4 + bh * 384;
        #pragma unroll
        for (int s = 0; s < 2; ++s) {
            int ow = lane + (s << 6);
            int j0 = 4 * ow - 2;
            bool edge = (j0 < 0) | (j0 + 7 > 511);
            float sc = edge ? RESC : 1.f;
            float wk[8]; int jj[8];
            #pragma unroll
            for (int k = 0; k < 8; ++k) {
                int j = j0 + k;
                wk[k] = (((unsigned)j < 512u) ? W4k[k] : 0.f) * sc;
                jj[k] = SJ(iclamp_(j, 0, 511));
            }
            #pragma unroll
            for (int c = 0; c < 3; ++c) {
                const float* p = pl + c * PSTRIDE;
                float a = 0.f;
                #pragma unroll
                for (int k = 0; k < 8; ++k) a += wk[k] * p[jj[k]];
                o4[ow * 3 + c] = __float2half_rn(a);
            }
        }
    }
    if (xh8) {                                  // F=8: 1 output/lane
        const float W8k[16] = {0.0078125f, 0.0234375f, 0.0390625f, 0.0546875f,
                               0.0703125f, 0.0859375f, 0.1015625f, 0.1171875f,
                               0.1171875f, 0.1015625f, 0.0859375f, 0.0703125f,
                               0.0546875f, 0.0390625f, 0.0234375f, 0.0078125f};
        __half* o8 = xh8 + bh * 192;
        int ow = lane;
        int j0 = 8 * ow - 4;
        bool edge = (j0 < 0) | (j0 + 15 > 511);
        float sc = edge ? RESC : 1.f;
        float wk[16]; int jj[16];
        #pragma unroll
        for (int k = 0; k < 16; ++k) {
            int j = j0 + k;
            wk[k] = (((unsigned)j < 512u) ? W8k[k] : 0.f) * sc;
            jj[k] = SJ(iclamp_(j, 0, 511));
        }
        #pragma unroll
        for (int c = 0; c < 3; ++c) {
            const float* p = pl + c * PSTRIDE;
            float a = 0.f;
            #pragma unroll
            for (int k = 0; k < 16; ++k) a += wk[k] * p[jj[k]];
            o8[ow * 3 + c] = __float2half_rn(a);
        }
    }
}

// ---------------- per-level: LDS-staged vertical pass + conv + channel-sum ----------------
template <int F, int THB>
static __device__ __forceinline__ void level_body(const __half* __restrict__ xh,
                                                  const float* __restrict__ knorm_all, int lvl,
                                                  float* __restrict__ es, int bx, int by, int b,
                                                  char* smem_raw) {
    constexpr int TH = HH / F, TW = WW / F, TW3 = TW * 3, TAPS = 2 * F;
    constexpr int RS = (THB + 3) * F;
    constexpr int DR = THB + 2;
    __half* stg = (__half*)smem_raw;                          // [RS][108]
    float* dst = (float*)(smem_raw + RS * 108 * 2);           // [DR][108]
    float* wvv = dst + DR * 108;                              // [DR][TAPS]
    float* kn = wvv + DR * TAPS;                              // [27]
    int owb = bx * 32, ohb = by * THB;
    int tid = threadIdx.x;
    if (tid < 27) kn[tid] = knorm_all[lvl * 27 + tid];
    if (tid >= 32 && tid < 32 + DR) {
        int r = tid - 32;
        int oh = ohb - 1 + r;
        if (oh < 0 || oh >= TH) {
            #pragma unroll
            for (int k = 0; k < TAPS; ++k) wvv[r * TAPS + k] = 0.f;
        } else {
            float sfh = (oh + 0.5f) * F - 0.5f;
            int j0 = oh * F - F / 2;
            float tmp[TAPS]; float s = 0.f;
            #pragma unroll
            for (int k = 0; k < TAPS; ++k) {
                int j = j0 + k;
                float w = (j >= 0 && j < HH) ? (1.f - fabsf(j - sfh) * (1.0f / F)) : 0.f;
                tmp[k] = w; s += w;
            }
            float inv = 1.f / s;
            #pragma unroll
            for (int k = 0; k < TAPS; ++k) wvv[r * TAPS + k] = tmp[k] * inv;
        }
    }
    int jmin = (ohb - 1) * F - F / 2;
    int cb = owb * 3 - 4;
    bool fast = (cb >= 0) && (cb + 108 <= TW3);
    const __half* xb = xh + b * (HH * TW3);
    for (int i = tid; i < RS * 27; i += 256) {
        int r = i / 27;
        int c4 = (i - r * 27) * 4;
        int jh = iclamp_(jmin + r, 0, HH - 1);
        const __half* rp = xb + jh * TW3;
        if (fast) {
            *(ushort4*)&stg[r * 108 + c4] = *(const ushort4*)(rp + cb + c4);
        } else {
            #pragma unroll
            for (int u = 0; u < 4; ++u) {
                int col = iclamp_(cb + c4 + u, 0, TW3 - 1);
                stg[r * 108 + c4 + u] = rp[col];
            }
        }
    }
    __syncthreads();
    for (int i = tid; i < DR * 27; i += 256) {
        int r = i / 27;
        int c4 = (i - r * 27) * 4;
        int gc = cb + c4;
        float v0 = 0, v1 = 0, v2 = 0, v3 = 0;
        if ((unsigned)gc < (unsigned)TW3) {
            const __half* sp = &stg[r * F * 108 + c4];
            const float* wr = &wvv[r * TAPS];
            #pragma unroll
            for (int k = 0; k < TAPS; ++k) {
                float wk = wr[k];
                const __half2* h2 = (const __half2*)(sp + k * 108);
                float2 f0 = __half22float2(h2[0]);
                float2 f1 = __half22float2(h2[1]);
                v0 += wk * f0.x; v1 += wk * f0.y;
                v2 += wk * f1.x; v3 += wk * f1.y;
            }
        }
        float4 q; q.x = v0; q.y = v1; q.z = v2; q.w = v3;
        *(float4*)&dst[r * 108 + c4] = q;
    }
    __syncthreads();
    for (int i = tid; i < THB * 32; i += 256) {
        int wl = i & 31, hl = i >> 5;
        int base = hl * 108 + wl * 3 + 1;
        float e = 0.f;
        #pragma unroll
        for (int c = 0; c < 3; ++c) {
            float conv = 0.f;
            #pragma unroll
            for (int dh = 0; dh < 3; ++dh)
                #pragma unroll
                for (int dw = 0; dw < 3; ++dw)
                    conv += kn[(dh * 3 + dw) * 3 + c] * dst[base + dh * 108 + dw * 3 + c];
            e += dst[base + 108 + 3 + c] - conv;
        }
        es[b * (TH * TW) + (ohb + hl) * TW + owb + wl] = e;
    }
}

__global__ void levels_kernel(const __half* __restrict__ xh2, const __half* __restrict__ xh4,
                              const __half* __restrict__ xh8, const float* __restrict__ knorm,
                              float* __restrict__ es2, float* __restrict__ es3,
                              float* __restrict__ es4, int block_base) {
    __shared__ __align__(16) char smem[16896];
    int vb = blockIdx.x + block_base;
    if (vb < 4096) {
        level_body<2, 16>(xh2, knorm, 1, es2, vb & 7, (vb >> 3) & 15, vb >> 7, smem);
    } else if (vb < 6144) {
        int l = vb - 4096;
        level_body<4, 8>(xh4, knorm, 2, es3, l & 3, (l >> 2) & 15, l >> 6, smem);
    } else {
        int l = vb - 6144;
        level_body<8, 4>(xh8, knorm, 3, es4, l & 1, (l >> 1) & 15, l >> 5, smem);
    }
}

// ---------------- fused: level-1 residual + 3 upsampled levels, square, reduce ----------------
// x tile stored as 3 de-interleaved channel planes, odd stride 35 -> conflict-free b32 reads.
#define FPS 35
#define FPC (34 * FPS)   // 1190
__global__ void __launch_bounds__(256, 8)
fused_kernel(const float* __restrict__ x, const float* __restrict__ knorm,
             const float* __restrict__ es2, const float* __restrict__ es3,
             const float* __restrict__ es4, double* __restrict__ partials) {
    __shared__ __align__(16) float planes[3 * FPC];   // 3570 floats
    __shared__ float e2t[18 * 19];
    __shared__ float e3t[10 * 11];
    __shared__ float e4t[6 * 7];
    __shared__ float kn[27];
    __shared__ float smf[4];
    int b = blockIdx.z;
    int hb = blockIdx.y * 32, wb = blockIdx.x * 32;
    int tid = threadIdx.x;
    if (tid < 27) kn[tid] = knorm[tid];
    const float* xb = x + b * (HH * WW * CC);
    int cb = wb * 3 - 4;
    bool fastc = (cb >= 0) && (cb + 108 <= WW * CC);
    for (int i = tid; i < 918; i += 256) {
        int r = i / 27;
        int f0 = (i - r * 27) * 4;
        int gh = hb - 1 + r;
        bool ghv = (unsigned)gh < (unsigned)HH;
        float vv[4] = {0.f, 0.f, 0.f, 0.f};
        if (ghv) {
            const float* rp = xb + gh * (WW * CC);
            if (fastc) {
                float4 v = *(const float4*)(rp + cb + f0);
                vv[0] = v.x; vv[1] = v.y; vv[2] = v.z; vv[3] = v.w;
            } else {
                int g0 = cb + f0;
                #pragma unroll
                for (int u = 0; u < 4; ++u)
                    vv[u] = ((unsigned)(g0 + u) < (unsigned)(WW * CC)) ? rp[g0 + u] : 0.f;
            }
        }
        #pragma unroll
        for (int u = 0; u < 4; ++u) {
            int f = f0 + u;
            if (f >= 1 && f <= 102) {
                int lc = (f - 1) / 3;
                int ch = (f - 1) - lc * 3;
                planes[ch * FPC + r * FPS + lc] = vv[u];
            }
        }
    }
    {
        const float* e2b = es2 + b * (256 * 256);
        int h0 = hb / 2 - 1, w0 = wb / 2 - 1;
        for (int i = tid; i < 18 * 32; i += 256) {
            int r = i >> 5, c = i & 31;
            if (c < 18) {
                int gh = iclamp_(h0 + r, 0, 255);
                int gw = iclamp_(w0 + c, 0, 255);
                e2t[r * 19 + c] = e2b[gh * 256 + gw];
            }
        }
        const float* e3b = es3 + b * (128 * 128);
        int h03 = hb / 4 - 1, w03 = wb / 4 - 1;
        if (tid < 160) {
            int r = tid >> 4, c = tid & 15;
            if (c < 10) {
                int gh = iclamp_(h03 + r, 0, 127);
                int gw = iclamp_(w03 + c, 0, 127);
                e3t[r * 11 + c] = e3b[gh * 128 + gw];
            }
        }
        const float* e4b = es4 + b * (64 * 64);
        int h04 = hb / 8 - 1, w04 = wb / 8 - 1;
        if (tid < 48) {
            int r = tid >> 3, c = tid & 7;
            if (c < 6) {
                int gh = iclamp_(h04 + r, 0, 63);
                int gw = iclamp_(w04 + c, 0, 63);
                e4t[r * 7 + c] = e4b[gh * 64 + gw];
            }
        }
    }
    __syncthreads();

    int q = tid >> 3;        // output row 0..31
    int a = tid & 7;         // col group: cols 4a..4a+3
    float cv0 = 0, cv1 = 0, cv2 = 0, cv3 = 0;
    float ce0 = 0, ce1 = 0, ce2 = 0, ce3 = 0;
    #pragma unroll
    for (int c = 0; c < 3; ++c) {
        const float* P = planes + c * FPC;
        #pragma unroll
        for (int dh = 0; dh < 3; ++dh) {
            const float* r0 = P + (q + dh) * FPS + 4 * a;
            float w0 = r0[0], w1 = r0[1], w2 = r0[2], w3 = r0[3], w4 = r0[4], w5 = r0[5];
            float ka = kn[dh * 9 + c], kb = kn[dh * 9 + 3 + c], kc = kn[dh * 9 + 6 + c];
            cv0 += ka * w0 + kb * w1 + kc * w2;
            cv1 += ka * w1 + kb * w2 + kc * w3;
            cv2 += ka * w2 + kb * w3 + kc * w4;
            cv3 += ka * w3 + kb * w4 + kc * w5;
            if (dh == 1) { ce0 += w1; ce1 += w2; ce2 += w3; ce3 += w4; }
        }
    }
    float e[4] = {ce0 - cv0, ce1 - cv1, ce2 - cv2, ce3 - cv3};

    int n2 = q & 1;   float fh2 = n2 ? 0.25f : 0.75f;               int rh2 = (q >> 1) + n2;
    int n4 = q & 3;   float fh4 = ((n4 + 2) & 3) * 0.25f + 0.125f;  int rh4 = (q >> 2) + (n4 < 2 ? 0 : 1);
    int n8 = q & 7;   float fh8 = ((n8 + 4) & 7) * 0.125f + 0.0625f; int rh8 = (q >> 3) + (n8 < 4 ? 0 : 1);
    {   // L2: taps cols 2a..2a+3
        const float* r0 = &e2t[rh2 * 19 + 2 * a];
        const float* r1 = r0 + 19;
        float t0 = r0[0], t1 = r0[1], t2 = r0[2], t3 = r0[3];
        float b0 = r1[0], b1 = r1[1], b2 = r1[2], b3 = r1[3];
        float top, bot;
        top = t0 + 0.75f * (t1 - t0); bot = b0 + 0.75f * (b1 - b0); e[0] += top + fh2 * (bot - top);
        top = t1 + 0.25f * (t2 - t1); bot = b1 + 0.25f * (b2 - b1); e[1] += top + fh2 * (bot - top);
        top = t1 + 0.75f * (t2 - t1); bot = b1 + 0.75f * (b2 - b1); e[2] += top + fh2 * (bot - top);
        top = t2 + 0.25f * (t3 - t2); bot = b2 + 0.25f * (b3 - b2); e[3] += top + fh2 * (bot - top);
    }
    {   // L3: taps cols a..a+2
        const float* r0 = &e3t[rh4 * 11 + a];
        const float* r1 = r0 + 11;
        float t0 = r0[0], t1 = r0[1], t2 = r0[2];
        float b0 = r1[0], b1 = r1[1], b2 = r1[2];
        float top, bot;
        top = t0 + 0.625f * (t1 - t0); bot = b0 + 0.625f * (b1 - b0); e[0] += top + fh4 * (bot - top);
        top = t0 + 0.875f * (t1 - t0); bot = b0 + 0.875f * (b1 - b0); e[1] += top + fh4 * (bot - top);
        top = t1 + 0.125f * (t2 - t1); bot = b1 + 0.125f * (b2 - b1); e[2] += top + fh4 * (bot - top);
        top = t1 + 0.375f * (t2 - t1); bot = b1 + 0.375f * (b2 - b1); e[3] += top + fh4 * (bot - top);
    }
    {   // L4: one tap pair for all 4 px
        int rw8 = (a >> 1) + (a & 1);
        const float* r0 = &e4t[rh8 * 7 + rw8];
        const float* r1 = r0 + 7;
        float t0 = r0[0], t1 = r0[1];
        float b0 = r1[0], b1 = r1[1];
        float fwb = (a & 1) ? 0.0625f : 0.5625f;
        #pragma unroll
        for (int p = 0; p < 4; ++p) {
            float fw = fwb + 0.125f * p;
            float top = t0 + fw * (t1 - t0);
            float bot = b0 + fw * (b1 - b0);
            e[p] += top + fh8 * (bot - top);
        }
    }
    float acc = e[0] * e[0] + e[1] * e[1] + e[2] * e[2] + e[3] * e[3];
    #pragma unroll
    for (int off = 32; off; off >>= 1) acc += __shfl_down(acc, off);
    if ((tid & 63) == 0) smf[tid >> 6] = acc;
    __syncthreads();
    if (tid == 0) {
        double s = (double)smf[0] + (double)smf[1] + (double)smf[2] + (double)smf[3];
        partials[(b * 16 + blockIdx.y) * 16 + blockIdx.x] = s;
    }
}

__global__ void final_kernel(const double* __restrict__ partials, int n,
                             const double* __restrict__ kl, float* __restrict__ out) {
    __shared__ double sm[1024];
    double acc = 0.0;
    for (int i = threadIdx.x; i < n; i += 1024) acc += partials[i];
    sm[threadIdx.x] = acc;
    __syncthreads();
    for (int s = 512; s > 0; s >>= 1) {
        if (threadIdx.x < (unsigned)s) sm[threadIdx.x] += sm[threadIdx.x + s];
        __syncthreads();
    }
    if (threadIdx.x == 0) out[0] = (float)(sm[0] / (double)BB + (double)LL * kl[0]);
}

extern "C" void kernel_launch(void* const* d_in, const int* in_sizes, int n_in,
                              void* d_out, int out_size, void* d_ws, size_t ws_size,
                              hipStream_t stream) {
    const float* x = (const float*)d_in[0];
    const float* loc = (const float*)d_in[1];
    const float* scale = (const float*)d_in[2];
    const float* eps = (const float*)d_in[3];
    float* out = (float*)d_out;

    char* ws = (char*)d_ws;
    float* knorm = (float*)(ws + 0);
    double* kl = (double*)(ws + 512);
    double* partials = (double*)(ws + 1024);          // 8192*8 -> ends 66560
    float* es4 = (float*)(ws + 131072);               // 524288  -> 655360
    float* es3 = (float*)(ws + 655360);               // 2097152 -> 2752512
    float* es2 = (float*)(ws + 2752512);              // 8388608 -> 11141120
    (void)in_sizes; (void)n_in; (void)out_size;

    prep_kernel<<<1, 64, 0, stream>>>(loc, scale, eps, knorm, kl);

    const size_t SINGLE_NEED = 55181312ull;
    if (ws_size >= SINGLE_NEED) {
        __half* xh2 = (__half*)(ws + 11141120);       // 25165824 -> 36306944
        __half* xh4 = (__half*)(ws + 36306944);       // 12582912 -> 48889856
        __half* xh8 = (__half*)(ws + 48889856);       // 6291456  -> 55181312
        hpass_kernel<<<BB * HH / 4, 256, 0, stream>>>(x, xh2, xh4, xh8);
        levels_kernel<<<7168, 256, 0, stream>>>(xh2, xh4, xh8, knorm, es2, es3, es4, 0);
    } else {
        // split path: xh4+xh8 first, then xh2 reuses the same region (<= 36.3 MB peak)
        __half* xh4 = (__half*)(ws + 11141120);
        __half* xh8 = (__half*)(ws + 23724032);
        __half* xh2 = (__half*)(ws + 11141120);
        hpass_kernel<<<BB * HH / 4, 256, 0, stream>>>(x, nullptr, xh4, xh8);
        levels_kernel<<<3072, 256, 0, stream>>>(nullptr, xh4, xh8, knorm, es2, es3, es4, 4096);
        hpass_kernel<<<BB * HH / 4, 256, 0, stream>>>(x, xh2, nullptr, nullptr);
        levels_kernel<<<4096, 256, 0, stream>>>(xh2, nullptr, nullptr, knorm, es2, es3, es4, 0);
    }

    fused_kernel<<<dim3(16, 16, BB), 256, 0, stream>>>(x, knorm, es2, es3, es4, partials);
    final_kernel<<<1, 1024, 0, stream>>>(partials, 8192, kl, out);
}